// Round 1
// baseline (816.789 us; speedup 1.0000x reference)
//
#include <hip/hip_runtime.h>

#define N_NODES 100000
#define E_EDGES 1600000
#define DIN 256
#define C_OUT 64
#define NID_CNT 10000
#define NEG 0.2f

__device__ __forceinline__ unsigned fkey(float f) {
    unsigned u = __float_as_uint(f);
    return (u & 0x80000000u) ? ~u : (u | 0x80000000u);
}
__device__ __forceinline__ float fdec(unsigned k) {
    unsigned u = (k & 0x80000000u) ? (k & 0x7fffffffu) : ~k;
    return __uint_as_float(u);
}
__device__ __forceinline__ float lrelu(float x) { return x > 0.f ? x : NEG * x; }

// h = x @ W   (N x 256) @ (256 x 64) -> (N x 64)
// wave = 64 lanes = 64 output columns; 8 rows per wave; W staged in LDS in two
// 32KB k-chunks (keeps LDS <= 32KB -> 2 blocks/CU with 1024-thread blocks).
__global__ __launch_bounds__(1024) void k_gemm(const float* __restrict__ x,
                                               const float* __restrict__ W,
                                               float* __restrict__ h) {
    __shared__ float Ws[128 * C_OUT];  // 32 KB
    const int lane = threadIdx.x & 63;
    const int wid  = blockIdx.x * 16 + (threadIdx.x >> 6);
    const int r0   = wid * 8;
    const bool active = (r0 < N_NODES);
    const float* xp = x + (long)(active ? r0 : 0) * DIN;
    float acc[8] = {0.f,0.f,0.f,0.f,0.f,0.f,0.f,0.f};
    for (int kc = 0; kc < DIN; kc += 128) {
        for (int i = threadIdx.x; i < 128 * C_OUT; i += 1024)
            Ws[i] = W[kc * C_OUT + i];
        __syncthreads();
        if (active) {
            for (int k0 = 0; k0 < 128; k0 += 4) {
                float4 xv[8];
                #pragma unroll
                for (int r = 0; r < 8; ++r)
                    xv[r] = *(const float4*)(xp + r * DIN + kc + k0);
                #pragma unroll
                for (int j = 0; j < 4; ++j) {
                    float w = Ws[(k0 + j) * C_OUT + lane];
                    #pragma unroll
                    for (int r = 0; r < 8; ++r)
                        acc[r] += (&xv[r].x)[j] * w;
                }
            }
        }
        __syncthreads();
    }
    if (active) {
        #pragma unroll
        for (int r = 0; r < 8; ++r)
            h[(long)(r0 + r) * C_OUT + lane] = acc[r];
    }
}

// h[node_id[k]] += x[node_id[k]] @ W_id   (atomic: node_id may have duplicates)
__global__ __launch_bounds__(256) void k_id(const float* __restrict__ x,
                                            const float* __restrict__ Wid,
                                            const int* __restrict__ node_id,
                                            float* __restrict__ h) {
    __shared__ float Ws[128 * C_OUT];  // 32 KB
    const int lane = threadIdx.x & 63;
    const int wid  = blockIdx.x * 4 + (threadIdx.x >> 6);
    const int r0   = wid * 8;
    const bool active = (r0 < NID_CNT);
    int nodes[8];
    #pragma unroll
    for (int r = 0; r < 8; ++r)
        nodes[r] = active ? node_id[r0 + r] : 0;
    float acc[8] = {0.f,0.f,0.f,0.f,0.f,0.f,0.f,0.f};
    for (int kc = 0; kc < DIN; kc += 128) {
        for (int i = threadIdx.x; i < 128 * C_OUT; i += 256)
            Ws[i] = Wid[kc * C_OUT + i];
        __syncthreads();
        if (active) {
            for (int k0 = 0; k0 < 128; k0 += 4) {
                float4 xv[8];
                #pragma unroll
                for (int r = 0; r < 8; ++r)
                    xv[r] = *(const float4*)(x + (long)nodes[r] * DIN + kc + k0);
                #pragma unroll
                for (int j = 0; j < 4; ++j) {
                    float w = Ws[(k0 + j) * C_OUT + lane];
                    #pragma unroll
                    for (int r = 0; r < 8; ++r)
                        acc[r] += (&xv[r].x)[j] * w;
                }
            }
        }
        __syncthreads();
    }
    if (active) {
        #pragma unroll
        for (int r = 0; r < 8; ++r)
            atomicAdd(&h[(long)nodes[r] * C_OUT + lane], acc[r]);
    }
}

// per-node attention scalars: ad = h . att[:64], as = h . att[64:]; init max key
__global__ __launch_bounds__(256) void k_scores(const float* __restrict__ h,
                                                const float* __restrict__ att,
                                                float* __restrict__ ad,
                                                float* __restrict__ as,
                                                unsigned* __restrict__ mkey) {
    const int lane = threadIdx.x & 63;
    const int i = blockIdx.x * 4 + (threadIdx.x >> 6);
    if (i >= N_NODES) return;
    float v  = h[(long)i * C_OUT + lane];
    float p1 = v * att[lane];
    float p2 = v * att[C_OUT + lane];
    #pragma unroll
    for (int o = 32; o > 0; o >>= 1) {
        p1 += __shfl_xor(p1, o, 64);
        p2 += __shfl_xor(p2, o, 64);
    }
    if (lane == 0) {
        ad[i] = p1;
        as[i] = p2;
        mkey[i] = fkey(p2);  // self-loop source = i itself
    }
}

// segment max of as[src] over dst (leaky_relu monotone -> suffices)
__global__ __launch_bounds__(256) void k_max(const int* __restrict__ ei,
                                             const float* __restrict__ as,
                                             unsigned* __restrict__ mkey) {
    const int e = blockIdx.x * 256 + threadIdx.x;
    if (e >= E_EDGES) return;
    const int s = ei[e];
    const int d = ei[E_EDGES + e];
    atomicMax(&mkey[d], fkey(as[s]));
}

// finalize m, init denominator + out with the self-loop contribution
__global__ __launch_bounds__(256) void k_self(const float* __restrict__ h,
                                              const float* __restrict__ ad,
                                              const float* __restrict__ as,
                                              const unsigned* __restrict__ mkey,
                                              float* __restrict__ mf,
                                              float* __restrict__ sden,
                                              float* __restrict__ out) {
    const int lane = threadIdx.x & 63;
    const int i = blockIdx.x * 4 + (threadIdx.x >> 6);
    if (i >= N_NODES) return;
    float adi = ad[i];
    float m = lrelu(adi + fdec(mkey[i]));
    float wself = __expf(lrelu(adi + as[i]) - m);
    if (lane == 0) { mf[i] = m; sden[i] = wself; }
    out[(long)i * C_OUT + lane] = wself * h[(long)i * C_OUT + lane];
}

// per-edge scatter: out[dst] += w * h[src]; sden[dst] += w
__global__ __launch_bounds__(256) void k_edge(const int* __restrict__ ei,
                                              const float* __restrict__ h,
                                              const float* __restrict__ ad,
                                              const float* __restrict__ as,
                                              const float* __restrict__ mf,
                                              float* __restrict__ sden,
                                              float* __restrict__ out) {
    const int lane = threadIdx.x & 63;
    const int e = blockIdx.x * 4 + (threadIdx.x >> 6);
    if (e >= E_EDGES) return;
    const int s = ei[e];
    const int d = ei[E_EDGES + e];
    float w = __expf(lrelu(ad[d] + as[s]) - mf[d]);
    float val = w * h[(long)s * C_OUT + lane];
    atomicAdd(&out[(long)d * C_OUT + lane], val);
    if (lane == 0) atomicAdd(&sden[d], w);
}

__global__ __launch_bounds__(256) void k_norm(float* __restrict__ out,
                                              const float* __restrict__ sden) {
    const long idx = (long)blockIdx.x * 256 + threadIdx.x;
    if (idx >= (long)N_NODES * C_OUT) return;
    out[idx] /= (sden[idx >> 6] + 1e-16f);
}

extern "C" void kernel_launch(void* const* d_in, const int* in_sizes, int n_in,
                              void* d_out, int out_size, void* d_ws, size_t ws_size,
                              hipStream_t stream) {
    const float* x      = (const float*)d_in[0];
    const int*   ei     = (const int*)d_in[1];
    const int*   nid    = (const int*)d_in[2];
    const float* W      = (const float*)d_in[3];
    const float* Wid    = (const float*)d_in[4];
    const float* att    = (const float*)d_in[5];
    float* out = (float*)d_out;

    char* ws = (char*)d_ws;
    float*    h    = (float*)(ws);                         // 25,600,000 B
    float*    ad   = (float*)(ws + 25600000);              // 400,000 B
    float*    as   = (float*)(ws + 26000000);              // 400,000 B
    unsigned* mkey = (unsigned*)(ws + 26400000);           // 400,000 B
    float*    mf   = (float*)(ws + 26800000);              // 400,000 B
    float*    sden = (float*)(ws + 27200000);              // 400,000 B

    // h = x @ W
    k_gemm<<<782, 1024, 0, stream>>>(x, W, h);
    // h[node_id] += x[node_id] @ W_id
    k_id<<<313, 256, 0, stream>>>(x, Wid, nid, h);
    // per-node scalars
    k_scores<<<25000, 256, 0, stream>>>(h, att, ad, as, mkey);
    // segment max over edges
    k_max<<<6250, 256, 0, stream>>>(ei, as, mkey);
    // self-loop init of m, sden, out
    k_self<<<25000, 256, 0, stream>>>(h, ad, as, mkey, mf, sden, out);
    // edge scatter
    k_edge<<<400000, 256, 0, stream>>>(ei, h, ad, as, mf, sden, out);
    // normalize
    k_norm<<<25000, 256, 0, stream>>>(out, sden);
}

// Round 2
// 549.569 us; speedup vs baseline: 1.4862x; 1.4862x over previous
//
#include <hip/hip_runtime.h>

#define N_NODES 100000
#define E_EDGES 1600000
#define DIN 256
#define C_OUT 64
#define NID_CNT 10000
#define NEG 0.2f
#define NB_SCAN 98  // ceil(100000/1024)

__device__ __forceinline__ float lrelu(float x) { return x > 0.f ? x : NEG * x; }

// h = x @ W   (N x 256) @ (256 x 64) -> (N x 64)
__global__ __launch_bounds__(1024) void k_gemm(const float* __restrict__ x,
                                               const float* __restrict__ W,
                                               float* __restrict__ h) {
    __shared__ float Ws[128 * C_OUT];  // 32 KB
    const int lane = threadIdx.x & 63;
    const int wid  = blockIdx.x * 16 + (threadIdx.x >> 6);
    const int r0   = wid * 8;
    const bool active = (r0 < N_NODES);
    const float* xp = x + (long)(active ? r0 : 0) * DIN;
    float acc[8] = {0.f,0.f,0.f,0.f,0.f,0.f,0.f,0.f};
    for (int kc = 0; kc < DIN; kc += 128) {
        for (int i = threadIdx.x; i < 128 * C_OUT; i += 1024)
            Ws[i] = W[kc * C_OUT + i];
        __syncthreads();
        if (active) {
            for (int k0 = 0; k0 < 128; k0 += 4) {
                float4 xv[8];
                #pragma unroll
                for (int r = 0; r < 8; ++r)
                    xv[r] = *(const float4*)(xp + r * DIN + kc + k0);
                #pragma unroll
                for (int j = 0; j < 4; ++j) {
                    float w = Ws[(k0 + j) * C_OUT + lane];
                    #pragma unroll
                    for (int r = 0; r < 8; ++r)
                        acc[r] += (&xv[r].x)[j] * w;
                }
            }
        }
        __syncthreads();
    }
    if (active) {
        #pragma unroll
        for (int r = 0; r < 8; ++r)
            h[(long)(r0 + r) * C_OUT + lane] = acc[r];
    }
}

// h[node_id[k]] += x[node_id[k]] @ W_id  (atomic: duplicates possible)
__global__ __launch_bounds__(256) void k_id(const float* __restrict__ x,
                                            const float* __restrict__ Wid,
                                            const int* __restrict__ node_id,
                                            float* __restrict__ h) {
    __shared__ float Ws[128 * C_OUT];
    const int lane = threadIdx.x & 63;
    const int wid  = blockIdx.x * 4 + (threadIdx.x >> 6);
    const int r0   = wid * 8;
    const bool active = (r0 < NID_CNT);
    int nodes[8];
    #pragma unroll
    for (int r = 0; r < 8; ++r)
        nodes[r] = active ? node_id[r0 + r] : 0;
    float acc[8] = {0.f,0.f,0.f,0.f,0.f,0.f,0.f,0.f};
    for (int kc = 0; kc < DIN; kc += 128) {
        for (int i = threadIdx.x; i < 128 * C_OUT; i += 256)
            Ws[i] = Wid[kc * C_OUT + i];
        __syncthreads();
        if (active) {
            for (int k0 = 0; k0 < 128; k0 += 4) {
                float4 xv[8];
                #pragma unroll
                for (int r = 0; r < 8; ++r)
                    xv[r] = *(const float4*)(x + (long)nodes[r] * DIN + kc + k0);
                #pragma unroll
                for (int j = 0; j < 4; ++j) {
                    float w = Ws[(k0 + j) * C_OUT + lane];
                    #pragma unroll
                    for (int r = 0; r < 8; ++r)
                        acc[r] += (&xv[r].x)[j] * w;
                }
            }
        }
        __syncthreads();
    }
    if (active) {
        #pragma unroll
        for (int r = 0; r < 8; ++r)
            atomicAdd(&h[(long)nodes[r] * C_OUT + lane], acc[r]);
    }
}

// per-node attention scalars; also zero the degree histogram
__global__ __launch_bounds__(256) void k_scores(const float* __restrict__ h,
                                                const float* __restrict__ att,
                                                float* __restrict__ ad,
                                                float* __restrict__ as,
                                                int* __restrict__ deg) {
    const int lane = threadIdx.x & 63;
    const int i = blockIdx.x * 4 + (threadIdx.x >> 6);
    if (i >= N_NODES) return;
    float v  = h[(long)i * C_OUT + lane];
    float p1 = v * att[lane];
    float p2 = v * att[C_OUT + lane];
    #pragma unroll
    for (int o = 32; o > 0; o >>= 1) {
        p1 += __shfl_xor(p1, o, 64);
        p2 += __shfl_xor(p2, o, 64);
    }
    if (lane == 0) {
        ad[i] = p1;
        as[i] = p2;
        deg[i] = 0;
    }
}

// in-degree histogram
__global__ __launch_bounds__(1024) void k_hist(const int* __restrict__ ei,
                                               int* __restrict__ deg) {
    const int e = blockIdx.x * 1024 + threadIdx.x;
    if (e >= E_EDGES) return;
    atomicAdd(&deg[ei[E_EDGES + e]], 1);
}

// exclusive scan, 3 kernels
__global__ __launch_bounds__(1024) void k_scan1(const int* __restrict__ deg,
                                                int* __restrict__ cur,
                                                int* __restrict__ bsum) {
    __shared__ int tmp[1024];
    const int gid = blockIdx.x * 1024 + threadIdx.x;
    const int v = (gid < N_NODES) ? deg[gid] : 0;
    tmp[threadIdx.x] = v;
    __syncthreads();
    for (int o = 1; o < 1024; o <<= 1) {
        int t = (threadIdx.x >= o) ? tmp[threadIdx.x - o] : 0;
        __syncthreads();
        tmp[threadIdx.x] += t;
        __syncthreads();
    }
    if (gid < N_NODES) cur[gid] = tmp[threadIdx.x] - v;  // exclusive
    if (threadIdx.x == 1023) bsum[blockIdx.x] = tmp[1023];
}

__global__ __launch_bounds__(128) void k_scan2(int* __restrict__ bsum) {
    __shared__ int tmp[128];
    const int v = (threadIdx.x < NB_SCAN) ? bsum[threadIdx.x] : 0;
    tmp[threadIdx.x] = v;
    __syncthreads();
    for (int o = 1; o < 128; o <<= 1) {
        int t = (threadIdx.x >= o) ? tmp[threadIdx.x - o] : 0;
        __syncthreads();
        tmp[threadIdx.x] += t;
        __syncthreads();
    }
    if (threadIdx.x < NB_SCAN) bsum[threadIdx.x] = tmp[threadIdx.x] - v;
}

__global__ __launch_bounds__(1024) void k_scan3(int* __restrict__ cur,
                                                const int* __restrict__ bsum) {
    const int gid = blockIdx.x * 1024 + threadIdx.x;
    if (gid < N_NODES) cur[gid] += bsum[blockIdx.x];
}

// fill CSR: cur starts at segment start; after fill cur[d] == segment end
__global__ __launch_bounds__(1024) void k_fill(const int* __restrict__ ei,
                                               int* __restrict__ cur,
                                               int* __restrict__ csr) {
    const int e = blockIdx.x * 1024 + threadIdx.x;
    if (e >= E_EDGES) return;
    const int s = ei[e];
    const int d = ei[E_EDGES + e];
    const int pos = atomicAdd(&cur[d], 1);
    csr[pos] = s;
}

// gather: one wave per dst node; no atomics
__global__ __launch_bounds__(256) void k_gather(const int* __restrict__ cur,
                                                const int* __restrict__ csr,
                                                const float* __restrict__ h,
                                                const float* __restrict__ ad,
                                                const float* __restrict__ as,
                                                float* __restrict__ out) {
    const int lane = threadIdx.x & 63;
    const int i = blockIdx.x * 4 + (threadIdx.x >> 6);
    if (i >= N_NODES) return;
    const int end   = cur[i];
    const int start = (i > 0) ? cur[i - 1] : 0;
    const int deg   = end - start;
    const float adi = ad[i];
    const float asi = as[i];
    // pass 1: max of as over sources (incl self); lrelu monotone -> suffices
    float mx = asi;
    for (int b = 0; b < deg; b += 64) {
        int idx = b + lane;
        if (idx < deg) mx = fmaxf(mx, as[csr[start + idx]]);
    }
    #pragma unroll
    for (int o = 32; o > 0; o >>= 1) mx = fmaxf(mx, __shfl_xor(mx, o, 64));
    const float m = lrelu(adi + mx);
    const float wself = __expf(lrelu(adi + asi) - m);
    float acc = wself * h[(long)i * C_OUT + lane];
    float den = wself;
    for (int b = 0; b < deg; b += 64) {
        int idx = b + lane;
        int s = 0; float w = 0.f;
        if (idx < deg) {
            s = csr[start + idx];
            w = __expf(lrelu(adi + as[s]) - m);
        }
        const int cnt = min(64, deg - b);
        int j = 0;
        for (; j + 4 <= cnt; j += 4) {
            int   s0 = __shfl(s, j, 64),   s1 = __shfl(s, j+1, 64),
                  s2 = __shfl(s, j+2, 64), s3 = __shfl(s, j+3, 64);
            float w0 = __shfl(w, j, 64),   w1 = __shfl(w, j+1, 64),
                  w2 = __shfl(w, j+2, 64), w3 = __shfl(w, j+3, 64);
            float h0 = h[(long)s0 * C_OUT + lane];
            float h1 = h[(long)s1 * C_OUT + lane];
            float h2 = h[(long)s2 * C_OUT + lane];
            float h3 = h[(long)s3 * C_OUT + lane];
            acc += w0 * h0; acc += w1 * h1; acc += w2 * h2; acc += w3 * h3;
        }
        for (; j < cnt; ++j) {
            int   sj = __shfl(s, j, 64);
            float wj = __shfl(w, j, 64);
            acc += wj * h[(long)sj * C_OUT + lane];
        }
        float wsum = w;
        #pragma unroll
        for (int o = 32; o > 0; o >>= 1) wsum += __shfl_xor(wsum, o, 64);
        den += wsum;
    }
    out[(long)i * C_OUT + lane] = acc / (den + 1e-16f);
}

extern "C" void kernel_launch(void* const* d_in, const int* in_sizes, int n_in,
                              void* d_out, int out_size, void* d_ws, size_t ws_size,
                              hipStream_t stream) {
    const float* x   = (const float*)d_in[0];
    const int*   ei  = (const int*)d_in[1];
    const int*   nid = (const int*)d_in[2];
    const float* W   = (const float*)d_in[3];
    const float* Wid = (const float*)d_in[4];
    const float* att = (const float*)d_in[5];
    float* out = (float*)d_out;

    char* ws = (char*)d_ws;
    float* h    = (float*)(ws);                    // 25,600,000 B
    float* ad   = (float*)(ws + 25600000);         //    400,000 B
    float* as   = (float*)(ws + 26000000);         //    400,000 B
    int*   deg  = (int*)  (ws + 26400000);         //    400,000 B
    int*   cur  = (int*)  (ws + 26800000);         //    400,000 B
    int*   csr  = (int*)  (ws + 27200000);         //  6,400,000 B
    int*   bsum = (int*)  (ws + 33600000);         //        512 B

    k_gemm<<<782, 1024, 0, stream>>>(x, W, h);
    k_id<<<313, 256, 0, stream>>>(x, Wid, nid, h);
    k_scores<<<25000, 256, 0, stream>>>(h, att, ad, as, deg);
    k_hist<<<1563, 1024, 0, stream>>>(ei, deg);
    k_scan1<<<NB_SCAN, 1024, 0, stream>>>(deg, cur, bsum);
    k_scan2<<<1, 128, 0, stream>>>(bsum);
    k_scan3<<<NB_SCAN, 1024, 0, stream>>>(cur, bsum);
    k_fill<<<1563, 1024, 0, stream>>>(ei, cur, csr);
    k_gather<<<25000, 256, 0, stream>>>(cur, csr, h, ad, as, out);
}

// Round 3
// 393.724 us; speedup vs baseline: 2.0745x; 1.3958x over previous
//
#include <hip/hip_runtime.h>
#include <hip/hip_bf16.h>

#define N_NODES 100000
#define E_EDGES 1600000
#define DIN 256
#define C_OUT 64
#define NID_CNT 10000
#define NEG 0.2f
#define NB_SCAN 98  // ceil(100000/1024)
#define RB 128      // rows per block in GEMM
#define KC 64       // k-chunk

__device__ __forceinline__ float lrelu(float x) { return x > 0.f ? x : NEG * x; }
__device__ __forceinline__ float b2f(__hip_bfloat16 v) { return __bfloat162float(v); }

// h = x @ W : LDS-tiled. 256 thr, 128 rows x 64 cols per block, 4x8 per thread.
// x-tile XOR-swizzled (16B slots) -> <=2-way bank conflict on ds_read_b128.
__global__ __launch_bounds__(256) void k_gemm(const float* __restrict__ x,
                                              const float* __restrict__ W,
                                              float* __restrict__ h) {
    __shared__ float4 xs[RB][16];  // 32 KB; xs[r][kq ^ ((r>>2)&3)] = x[r0+r][kc+4kq..]
    __shared__ float4 ws[KC][16];  // 16 KB; ws[k][s] = W[kc+k][4s..]
    const int tid = threadIdx.x;
    const int rg = tid >> 3;   // 0..31 -> rows 4rg..4rg+3
    const int cg = tid & 7;    // cols 8cg..8cg+7
    const int r0 = blockIdx.x * RB;
    float acc[4][8] = {};
    for (int kc = 0; kc < DIN; kc += KC) {
        #pragma unroll
        for (int i = 0; i < 8; ++i) {           // stage x: 2048 float4
            int f = tid + i * 256;
            int row = f >> 4, slot = f & 15;
            int grow = r0 + row;
            float4 v = make_float4(0.f, 0.f, 0.f, 0.f);
            if (grow < N_NODES) v = *(const float4*)(x + (long)grow * DIN + kc + slot * 4);
            xs[row][slot ^ ((row >> 2) & 3)] = v;
        }
        #pragma unroll
        for (int i = 0; i < 4; ++i) {           // stage W: 1024 float4
            int f = tid + i * 256;
            int k = f >> 4, slot = f & 15;
            ws[k][slot] = *(const float4*)(W + (long)(kc + k) * C_OUT + slot * 4);
        }
        __syncthreads();
        #pragma unroll
        for (int kq = 0; kq < 16; ++kq) {
            float4 xv[4];
            #pragma unroll
            for (int rr = 0; rr < 4; ++rr)
                xv[rr] = xs[rg * 4 + rr][kq ^ (rg & 3)];
            #pragma unroll
            for (int kk = 0; kk < 4; ++kk) {
                float4 w0 = ws[kq * 4 + kk][cg * 2];
                float4 w1 = ws[kq * 4 + kk][cg * 2 + 1];
                #pragma unroll
                for (int rr = 0; rr < 4; ++rr) {
                    float xr = (&xv[rr].x)[kk];
                    acc[rr][0] += xr * w0.x; acc[rr][1] += xr * w0.y;
                    acc[rr][2] += xr * w0.z; acc[rr][3] += xr * w0.w;
                    acc[rr][4] += xr * w1.x; acc[rr][5] += xr * w1.y;
                    acc[rr][6] += xr * w1.z; acc[rr][7] += xr * w1.w;
                }
            }
        }
        __syncthreads();
    }
    #pragma unroll
    for (int rr = 0; rr < 4; ++rr) {
        int orow = r0 + rg * 4 + rr;
        if (orow < N_NODES) {
            float4 o0 = make_float4(acc[rr][0], acc[rr][1], acc[rr][2], acc[rr][3]);
            float4 o1 = make_float4(acc[rr][4], acc[rr][5], acc[rr][6], acc[rr][7]);
            *(float4*)(h + (long)orow * C_OUT + cg * 8)     = o0;
            *(float4*)(h + (long)orow * C_OUT + cg * 8 + 4) = o1;
        }
    }
}

// h[node_id[k]] += x[node_id[k]] @ W_id  (same tiling, indirect rows, atomic out)
__global__ __launch_bounds__(256) void k_id(const float* __restrict__ x,
                                            const float* __restrict__ Wid,
                                            const int* __restrict__ node_id,
                                            float* __restrict__ h) {
    __shared__ float4 xs[RB][16];
    __shared__ float4 ws[KC][16];
    __shared__ int rows[RB];
    const int tid = threadIdx.x;
    const int rg = tid >> 3;
    const int cg = tid & 7;
    const int r0 = blockIdx.x * RB;
    if (tid < RB) rows[tid] = (r0 + tid < NID_CNT) ? node_id[r0 + tid] : -1;
    __syncthreads();
    float acc[4][8] = {};
    for (int kc = 0; kc < DIN; kc += KC) {
        #pragma unroll
        for (int i = 0; i < 8; ++i) {
            int f = tid + i * 256;
            int row = f >> 4, slot = f & 15;
            int gr = rows[row];
            float4 v = make_float4(0.f, 0.f, 0.f, 0.f);
            if (gr >= 0) v = *(const float4*)(x + (long)gr * DIN + kc + slot * 4);
            xs[row][slot ^ ((row >> 2) & 3)] = v;
        }
        #pragma unroll
        for (int i = 0; i < 4; ++i) {
            int f = tid + i * 256;
            int k = f >> 4, slot = f & 15;
            ws[k][slot] = *(const float4*)(Wid + (long)(kc + k) * C_OUT + slot * 4);
        }
        __syncthreads();
        #pragma unroll
        for (int kq = 0; kq < 16; ++kq) {
            float4 xv[4];
            #pragma unroll
            for (int rr = 0; rr < 4; ++rr)
                xv[rr] = xs[rg * 4 + rr][kq ^ (rg & 3)];
            #pragma unroll
            for (int kk = 0; kk < 4; ++kk) {
                float4 w0 = ws[kq * 4 + kk][cg * 2];
                float4 w1 = ws[kq * 4 + kk][cg * 2 + 1];
                #pragma unroll
                for (int rr = 0; rr < 4; ++rr) {
                    float xr = (&xv[rr].x)[kk];
                    acc[rr][0] += xr * w0.x; acc[rr][1] += xr * w0.y;
                    acc[rr][2] += xr * w0.z; acc[rr][3] += xr * w0.w;
                    acc[rr][4] += xr * w1.x; acc[rr][5] += xr * w1.y;
                    acc[rr][6] += xr * w1.z; acc[rr][7] += xr * w1.w;
                }
            }
        }
        __syncthreads();
    }
    #pragma unroll
    for (int rr = 0; rr < 4; ++rr) {
        int gr = rows[rg * 4 + rr];
        if (gr >= 0) {
            #pragma unroll
            for (int c = 0; c < 8; ++c)
                atomicAdd(&h[(long)gr * C_OUT + cg * 8 + c], acc[rr][c]);
        }
    }
}

// per-node attention scalars + bf16 copy of h
__global__ __launch_bounds__(256) void k_scores(const float* __restrict__ h,
                                                const float* __restrict__ att,
                                                float* __restrict__ ad,
                                                float* __restrict__ as,
                                                __hip_bfloat16* __restrict__ hb) {
    const int lane = threadIdx.x & 63;
    const int i = blockIdx.x * 4 + (threadIdx.x >> 6);
    if (i >= N_NODES) return;
    float v = h[(long)i * C_OUT + lane];
    hb[(long)i * C_OUT + lane] = __float2bfloat16(v);
    float p1 = v * att[lane];
    float p2 = v * att[C_OUT + lane];
    #pragma unroll
    for (int o = 32; o > 0; o >>= 1) {
        p1 += __shfl_xor(p1, o, 64);
        p2 += __shfl_xor(p2, o, 64);
    }
    if (lane == 0) { ad[i] = p1; as[i] = p2; }
}

__global__ __launch_bounds__(1024) void k_hist(const int* __restrict__ ei,
                                               int* __restrict__ deg) {
    const int e = blockIdx.x * 1024 + threadIdx.x;
    if (e >= E_EDGES) return;
    atomicAdd(&deg[ei[E_EDGES + e]], 1);
}

__global__ __launch_bounds__(1024) void k_scan1(const int* __restrict__ deg,
                                                int* __restrict__ cur,
                                                int* __restrict__ bsum) {
    __shared__ int tmp[1024];
    const int gid = blockIdx.x * 1024 + threadIdx.x;
    const int v = (gid < N_NODES) ? deg[gid] : 0;
    tmp[threadIdx.x] = v;
    __syncthreads();
    for (int o = 1; o < 1024; o <<= 1) {
        int t = (threadIdx.x >= o) ? tmp[threadIdx.x - o] : 0;
        __syncthreads();
        tmp[threadIdx.x] += t;
        __syncthreads();
    }
    if (gid < N_NODES) cur[gid] = tmp[threadIdx.x] - v;
    if (threadIdx.x == 1023) bsum[blockIdx.x] = tmp[1023];
}

__global__ __launch_bounds__(128) void k_scan2(int* __restrict__ bsum) {
    __shared__ int tmp[128];
    const int v = (threadIdx.x < NB_SCAN) ? bsum[threadIdx.x] : 0;
    tmp[threadIdx.x] = v;
    __syncthreads();
    for (int o = 1; o < 128; o <<= 1) {
        int t = (threadIdx.x >= o) ? tmp[threadIdx.x - o] : 0;
        __syncthreads();
        tmp[threadIdx.x] += t;
        __syncthreads();
    }
    if (threadIdx.x < NB_SCAN) bsum[threadIdx.x] = tmp[threadIdx.x] - v;
}

__global__ __launch_bounds__(1024) void k_scan3(int* __restrict__ cur,
                                                const int* __restrict__ bsum) {
    const int gid = blockIdx.x * 1024 + threadIdx.x;
    if (gid < N_NODES) cur[gid] += bsum[blockIdx.x];
}

__global__ __launch_bounds__(1024) void k_fill(const int* __restrict__ ei,
                                               int* __restrict__ cur,
                                               int* __restrict__ csr) {
    const int e = blockIdx.x * 1024 + threadIdx.x;
    if (e >= E_EDGES) return;
    const int s = ei[e];
    const int d = ei[E_EDGES + e];
    const int pos = atomicAdd(&cur[d], 1);
    csr[pos] = s;
}

// gather: one wave per dst; deg<=64 fast path loads CSR once; bf16 h rows
__global__ __launch_bounds__(256) void k_gather(const int* __restrict__ cur,
                                                const int* __restrict__ csr,
                                                const __hip_bfloat16* __restrict__ hb,
                                                const float* __restrict__ ad,
                                                const float* __restrict__ as,
                                                float* __restrict__ out) {
    const int lane = threadIdx.x & 63;
    const int i = blockIdx.x * 4 + (threadIdx.x >> 6);
    if (i >= N_NODES) return;
    const int end   = cur[i];
    const int start = (i > 0) ? cur[i - 1] : 0;
    const int deg   = end - start;
    const float adi = ad[i];
    const float asi = as[i];
    float acc, den;
    if (deg <= 64) {
        int s = 0; float a = -1e30f;
        if (lane < deg) { s = csr[start + lane]; a = as[s]; }
        float mx = fmaxf(a, asi);
        #pragma unroll
        for (int o = 32; o > 0; o >>= 1) mx = fmaxf(mx, __shfl_xor(mx, o, 64));
        const float m = lrelu(adi + mx);
        float w = (lane < deg) ? __expf(lrelu(adi + a) - m) : 0.f;
        const float wself = __expf(lrelu(adi + asi) - m);
        float wsum = w;
        #pragma unroll
        for (int o = 32; o > 0; o >>= 1) wsum += __shfl_xor(wsum, o, 64);
        den = wself + wsum;
        acc = wself * b2f(hb[(long)i * C_OUT + lane]);
        int j = 0;
        for (; j + 4 <= deg; j += 4) {
            int   s0 = __shfl(s, j, 64),   s1 = __shfl(s, j + 1, 64),
                  s2 = __shfl(s, j + 2, 64), s3 = __shfl(s, j + 3, 64);
            float w0 = __shfl(w, j, 64),   w1 = __shfl(w, j + 1, 64),
                  w2 = __shfl(w, j + 2, 64), w3 = __shfl(w, j + 3, 64);
            float h0 = b2f(hb[(long)s0 * C_OUT + lane]);
            float h1 = b2f(hb[(long)s1 * C_OUT + lane]);
            float h2 = b2f(hb[(long)s2 * C_OUT + lane]);
            float h3 = b2f(hb[(long)s3 * C_OUT + lane]);
            acc += w0 * h0; acc += w1 * h1; acc += w2 * h2; acc += w3 * h3;
        }
        for (; j < deg; ++j) {
            int   sj = __shfl(s, j, 64);
            float wj = __shfl(w, j, 64);
            acc += wj * b2f(hb[(long)sj * C_OUT + lane]);
        }
    } else {  // rare generic path
        float mx = asi;
        for (int b = 0; b < deg; b += 64) {
            int idx = b + lane;
            if (idx < deg) mx = fmaxf(mx, as[csr[start + idx]]);
        }
        #pragma unroll
        for (int o = 32; o > 0; o >>= 1) mx = fmaxf(mx, __shfl_xor(mx, o, 64));
        const float m = lrelu(adi + mx);
        const float wself = __expf(lrelu(adi + asi) - m);
        acc = wself * b2f(hb[(long)i * C_OUT + lane]);
        den = wself;
        for (int b = 0; b < deg; b += 64) {
            int idx = b + lane;
            int s = 0; float w = 0.f;
            if (idx < deg) {
                s = csr[start + idx];
                w = __expf(lrelu(adi + as[s]) - m);
            }
            const int cnt = min(64, deg - b);
            for (int j = 0; j < cnt; ++j) {
                int   sj = __shfl(s, j, 64);
                float wj = __shfl(w, j, 64);
                acc += wj * b2f(hb[(long)sj * C_OUT + lane]);
            }
            float wsum = w;
            #pragma unroll
            for (int o = 32; o > 0; o >>= 1) wsum += __shfl_xor(wsum, o, 64);
            den += wsum;
        }
    }
    out[(long)i * C_OUT + lane] = acc / (den + 1e-16f);
}

extern "C" void kernel_launch(void* const* d_in, const int* in_sizes, int n_in,
                              void* d_out, int out_size, void* d_ws, size_t ws_size,
                              hipStream_t stream) {
    const float* x   = (const float*)d_in[0];
    const int*   ei  = (const int*)d_in[1];
    const int*   nid = (const int*)d_in[2];
    const float* W   = (const float*)d_in[3];
    const float* Wid = (const float*)d_in[4];
    const float* att = (const float*)d_in[5];
    float* out = (float*)d_out;

    char* ws = (char*)d_ws;
    float* h    = (float*)(ws);                          // 25,600,000 B
    float* ad   = (float*)(ws + 25600000);               //    400,000 B
    float* as   = (float*)(ws + 26000000);               //    400,000 B
    int*   deg  = (int*)  (ws + 26400000);               //    400,000 B
    int*   cur  = (int*)  (ws + 26800000);               //    400,000 B
    int*   csr  = (int*)  (ws + 27200000);               //  6,400,000 B
    int*   bsum = (int*)  (ws + 33600000);               //        512 B
    __hip_bfloat16* hb = (__hip_bfloat16*)(ws + 33600512);  // 12,800,000 B

    // CSR construction (independent of h)
    hipMemsetAsync(deg, 0, N_NODES * sizeof(int), stream);
    k_hist<<<1563, 1024, 0, stream>>>(ei, deg);
    k_scan1<<<NB_SCAN, 1024, 0, stream>>>(deg, cur, bsum);
    k_scan2<<<1, 128, 0, stream>>>(bsum);
    k_scan3<<<NB_SCAN, 1024, 0, stream>>>(cur, bsum);
    k_fill<<<1563, 1024, 0, stream>>>(ei, cur, csr);
    // feature path
    k_gemm<<<782, 256, 0, stream>>>(x, W, h);
    k_id<<<79, 256, 0, stream>>>(x, Wid, nid, h);
    k_scores<<<25000, 256, 0, stream>>>(h, att, ad, as, hb);
    k_gather<<<25000, 256, 0, stream>>>(cur, csr, hb, ad, as, out);
}

// Round 4
// 254.157 us; speedup vs baseline: 3.2137x; 1.5491x over previous
//
#include <hip/hip_runtime.h>
#include <hip/hip_bf16.h>

#define N_NODES 100000
#define E_EDGES 1600000
#define DIN 256
#define C_OUT 64
#define NID_CNT 10000
#define NEG 0.2f
#define RB 128      // rows per block in GEMM
#define KC 64       // k-chunk
#define NBUCK 391   // ceil(N_NODES/256) coarse buckets (dst >> 8)
#define NBINBLK 391 // ceil(E_EDGES/4096)

__device__ __forceinline__ float lrelu(float x) { return x > 0.f ? x : NEG * x; }
__device__ __forceinline__ float b2f(__hip_bfloat16 v) { return __bfloat162float(v); }

// ---------------- CSR build: two-level counting sort ----------------

// coarse bucket histogram (LDS-aggregated)
__global__ __launch_bounds__(256) void k_bhist(const int* __restrict__ ei,
                                               int* __restrict__ bkcnt) {
    __shared__ int cnt[NBUCK];
    const int tid = threadIdx.x;
    for (int i = tid; i < NBUCK; i += 256) cnt[i] = 0;
    __syncthreads();
    const int e0 = blockIdx.x * 4096;
    #pragma unroll
    for (int j = 0; j < 16; ++j) {
        int e = e0 + j * 256 + tid;
        if (e < E_EDGES) atomicAdd(&cnt[ei[E_EDGES + e] >> 8], 1);
    }
    __syncthreads();
    for (int i = tid; i < NBUCK; i += 256)
        if (cnt[i]) atomicAdd(&bkcnt[i], cnt[i]);
}

// scan 391 bucket counts -> bkoff (exclusive, +total at [NBUCK]), init bkcur
__global__ __launch_bounds__(512) void k_bscan(const int* __restrict__ bkcnt,
                                               int* __restrict__ bkoff,
                                               int* __restrict__ bkcur) {
    __shared__ int tmp[512];
    const int tid = threadIdx.x;
    const int v = (tid < NBUCK) ? bkcnt[tid] : 0;
    tmp[tid] = v;
    __syncthreads();
    for (int o = 1; o < 512; o <<= 1) {
        int t = (tid >= o) ? tmp[tid - o] : 0;
        __syncthreads();
        tmp[tid] += t;
        __syncthreads();
    }
    if (tid < NBUCK) {
        int excl = tmp[tid] - v;
        bkoff[tid] = excl;
        bkcur[tid] = excl;
        if (tid == NBUCK - 1) bkoff[NBUCK] = tmp[tid];
    }
}

// bin edges into coarse bucket regions; block reserves ranges with 1 atomic/bucket
__global__ __launch_bounds__(256) void k_bin(const int* __restrict__ ei,
                                             int* __restrict__ bkcur,
                                             int2* __restrict__ binned) {
    __shared__ int cnt[NBUCK];
    __shared__ int base[NBUCK];
    __shared__ int lcur[NBUCK];
    const int tid = threadIdx.x;
    for (int i = tid; i < NBUCK; i += 256) cnt[i] = 0;
    __syncthreads();
    const int e0 = blockIdx.x * 4096;
    int s[16], d[16];
    #pragma unroll
    for (int j = 0; j < 16; ++j) {
        int e = e0 + j * 256 + tid;
        if (e < E_EDGES) {
            s[j] = ei[e];
            d[j] = ei[E_EDGES + e];
            atomicAdd(&cnt[d[j] >> 8], 1);
        } else d[j] = -1;
    }
    __syncthreads();
    for (int i = tid; i < NBUCK; i += 256) {
        base[i] = cnt[i] ? atomicAdd(&bkcur[i], cnt[i]) : 0;
        lcur[i] = 0;
    }
    __syncthreads();
    #pragma unroll
    for (int j = 0; j < 16; ++j) {
        if (d[j] >= 0) {
            int b = d[j] >> 8;
            int r = atomicAdd(&lcur[b], 1);
            binned[base[b] + r] = make_int2(s[j], d[j]);
        }
    }
}

// one block per bucket: per-node LDS hist + scan; coalesced cur; L2-local csr scatter
__global__ __launch_bounds__(256) void k_place(const int2* __restrict__ binned,
                                               const int* __restrict__ bkoff,
                                               int* __restrict__ csr,
                                               int* __restrict__ cur) {
    __shared__ int ncnt[256];
    __shared__ int tmp[256];
    __shared__ int ncur[256];
    const int tid = threadIdx.x;
    const int b = blockIdx.x;
    const int lo = bkoff[b], hi = bkoff[b + 1];
    const int node0 = b << 8;
    ncnt[tid] = 0;
    __syncthreads();
    for (int e = lo + tid; e < hi; e += 256)
        atomicAdd(&ncnt[binned[e].y - node0], 1);
    __syncthreads();
    const int v = ncnt[tid];
    tmp[tid] = v;
    __syncthreads();
    for (int o = 1; o < 256; o <<= 1) {
        int t = (tid >= o) ? tmp[tid - o] : 0;
        __syncthreads();
        tmp[tid] += t;
        __syncthreads();
    }
    const int incl = tmp[tid];
    if (node0 + tid < N_NODES) cur[node0 + tid] = lo + incl;  // inclusive end
    ncur[tid] = incl - v;  // exclusive start
    __syncthreads();
    for (int e = lo + tid; e < hi; e += 256) {
        int2 p = binned[e];
        int r = atomicAdd(&ncur[p.y - node0], 1);
        csr[lo + r] = p.x;
    }
}

// ---------------- feature path ----------------

// h = x @ W : LDS-tiled. 256 thr, 128 rows x 64 cols per block, 4x8 per thread.
__global__ __launch_bounds__(256) void k_gemm(const float* __restrict__ x,
                                              const float* __restrict__ W,
                                              float* __restrict__ h) {
    __shared__ float4 xs[RB][16];
    __shared__ float4 ws[KC][16];
    const int tid = threadIdx.x;
    const int rg = tid >> 3;
    const int cg = tid & 7;
    const int r0 = blockIdx.x * RB;
    float acc[4][8] = {};
    for (int kc = 0; kc < DIN; kc += KC) {
        #pragma unroll
        for (int i = 0; i < 8; ++i) {
            int f = tid + i * 256;
            int row = f >> 4, slot = f & 15;
            int grow = r0 + row;
            float4 v = make_float4(0.f, 0.f, 0.f, 0.f);
            if (grow < N_NODES) v = *(const float4*)(x + (long)grow * DIN + kc + slot * 4);
            xs[row][slot ^ ((row >> 2) & 3)] = v;
        }
        #pragma unroll
        for (int i = 0; i < 4; ++i) {
            int f = tid + i * 256;
            int k = f >> 4, slot = f & 15;
            ws[k][slot] = *(const float4*)(W + (long)(kc + k) * C_OUT + slot * 4);
        }
        __syncthreads();
        #pragma unroll
        for (int kq = 0; kq < 16; ++kq) {
            float4 xv[4];
            #pragma unroll
            for (int rr = 0; rr < 4; ++rr)
                xv[rr] = xs[rg * 4 + rr][kq ^ (rg & 3)];
            #pragma unroll
            for (int kk = 0; kk < 4; ++kk) {
                float4 w0 = ws[kq * 4 + kk][cg * 2];
                float4 w1 = ws[kq * 4 + kk][cg * 2 + 1];
                #pragma unroll
                for (int rr = 0; rr < 4; ++rr) {
                    float xr = (&xv[rr].x)[kk];
                    acc[rr][0] += xr * w0.x; acc[rr][1] += xr * w0.y;
                    acc[rr][2] += xr * w0.z; acc[rr][3] += xr * w0.w;
                    acc[rr][4] += xr * w1.x; acc[rr][5] += xr * w1.y;
                    acc[rr][6] += xr * w1.z; acc[rr][7] += xr * w1.w;
                }
            }
        }
        __syncthreads();
    }
    #pragma unroll
    for (int rr = 0; rr < 4; ++rr) {
        int orow = r0 + rg * 4 + rr;
        if (orow < N_NODES) {
            float4 o0 = make_float4(acc[rr][0], acc[rr][1], acc[rr][2], acc[rr][3]);
            float4 o1 = make_float4(acc[rr][4], acc[rr][5], acc[rr][6], acc[rr][7]);
            *(float4*)(h + (long)orow * C_OUT + cg * 8)     = o0;
            *(float4*)(h + (long)orow * C_OUT + cg * 8 + 4) = o1;
        }
    }
}

__global__ __launch_bounds__(256) void k_id(const float* __restrict__ x,
                                            const float* __restrict__ Wid,
                                            const int* __restrict__ node_id,
                                            float* __restrict__ h) {
    __shared__ float4 xs[RB][16];
    __shared__ float4 ws[KC][16];
    __shared__ int rows[RB];
    const int tid = threadIdx.x;
    const int rg = tid >> 3;
    const int cg = tid & 7;
    const int r0 = blockIdx.x * RB;
    if (tid < RB) rows[tid] = (r0 + tid < NID_CNT) ? node_id[r0 + tid] : -1;
    __syncthreads();
    float acc[4][8] = {};
    for (int kc = 0; kc < DIN; kc += KC) {
        #pragma unroll
        for (int i = 0; i < 8; ++i) {
            int f = tid + i * 256;
            int row = f >> 4, slot = f & 15;
            int gr = rows[row];
            float4 v = make_float4(0.f, 0.f, 0.f, 0.f);
            if (gr >= 0) v = *(const float4*)(x + (long)gr * DIN + kc + slot * 4);
            xs[row][slot ^ ((row >> 2) & 3)] = v;
        }
        #pragma unroll
        for (int i = 0; i < 4; ++i) {
            int f = tid + i * 256;
            int k = f >> 4, slot = f & 15;
            ws[k][slot] = *(const float4*)(Wid + (long)(kc + k) * C_OUT + slot * 4);
        }
        __syncthreads();
        #pragma unroll
        for (int kq = 0; kq < 16; ++kq) {
            float4 xv[4];
            #pragma unroll
            for (int rr = 0; rr < 4; ++rr)
                xv[rr] = xs[rg * 4 + rr][kq ^ (rg & 3)];
            #pragma unroll
            for (int kk = 0; kk < 4; ++kk) {
                float4 w0 = ws[kq * 4 + kk][cg * 2];
                float4 w1 = ws[kq * 4 + kk][cg * 2 + 1];
                #pragma unroll
                for (int rr = 0; rr < 4; ++rr) {
                    float xr = (&xv[rr].x)[kk];
                    acc[rr][0] += xr * w0.x; acc[rr][1] += xr * w0.y;
                    acc[rr][2] += xr * w0.z; acc[rr][3] += xr * w0.w;
                    acc[rr][4] += xr * w1.x; acc[rr][5] += xr * w1.y;
                    acc[rr][6] += xr * w1.z; acc[rr][7] += xr * w1.w;
                }
            }
        }
        __syncthreads();
    }
    #pragma unroll
    for (int rr = 0; rr < 4; ++rr) {
        int gr = rows[rg * 4 + rr];
        if (gr >= 0) {
            #pragma unroll
            for (int c = 0; c < 8; ++c)
                atomicAdd(&h[(long)gr * C_OUT + cg * 8 + c], acc[rr][c]);
        }
    }
}

__global__ __launch_bounds__(256) void k_scores(const float* __restrict__ h,
                                                const float* __restrict__ att,
                                                float* __restrict__ ad,
                                                float* __restrict__ as,
                                                __hip_bfloat16* __restrict__ hb) {
    const int lane = threadIdx.x & 63;
    const int i = blockIdx.x * 4 + (threadIdx.x >> 6);
    if (i >= N_NODES) return;
    float v = h[(long)i * C_OUT + lane];
    hb[(long)i * C_OUT + lane] = __float2bfloat16(v);
    float p1 = v * att[lane];
    float p2 = v * att[C_OUT + lane];
    #pragma unroll
    for (int o = 32; o > 0; o >>= 1) {
        p1 += __shfl_xor(p1, o, 64);
        p2 += __shfl_xor(p2, o, 64);
    }
    if (lane == 0) { ad[i] = p1; as[i] = p2; }
}

__global__ __launch_bounds__(256) void k_gather(const int* __restrict__ cur,
                                                const int* __restrict__ csr,
                                                const __hip_bfloat16* __restrict__ hb,
                                                const float* __restrict__ ad,
                                                const float* __restrict__ as,
                                                float* __restrict__ out) {
    const int lane = threadIdx.x & 63;
    const int i = blockIdx.x * 4 + (threadIdx.x >> 6);
    if (i >= N_NODES) return;
    const int end   = cur[i];
    const int start = (i > 0) ? cur[i - 1] : 0;
    const int deg   = end - start;
    const float adi = ad[i];
    const float asi = as[i];
    float acc, den;
    if (deg <= 64) {
        int s = 0; float a = -1e30f;
        if (lane < deg) { s = csr[start + lane]; a = as[s]; }
        float mx = fmaxf(a, asi);
        #pragma unroll
        for (int o = 32; o > 0; o >>= 1) mx = fmaxf(mx, __shfl_xor(mx, o, 64));
        const float m = lrelu(adi + mx);
        float w = (lane < deg) ? __expf(lrelu(adi + a) - m) : 0.f;
        const float wself = __expf(lrelu(adi + asi) - m);
        float wsum = w;
        #pragma unroll
        for (int o = 32; o > 0; o >>= 1) wsum += __shfl_xor(wsum, o, 64);
        den = wself + wsum;
        acc = wself * b2f(hb[(long)i * C_OUT + lane]);
        int j = 0;
        for (; j + 4 <= deg; j += 4) {
            int   s0 = __shfl(s, j, 64),   s1 = __shfl(s, j + 1, 64),
                  s2 = __shfl(s, j + 2, 64), s3 = __shfl(s, j + 3, 64);
            float w0 = __shfl(w, j, 64),   w1 = __shfl(w, j + 1, 64),
                  w2 = __shfl(w, j + 2, 64), w3 = __shfl(w, j + 3, 64);
            float h0 = b2f(hb[(long)s0 * C_OUT + lane]);
            float h1 = b2f(hb[(long)s1 * C_OUT + lane]);
            float h2 = b2f(hb[(long)s2 * C_OUT + lane]);
            float h3 = b2f(hb[(long)s3 * C_OUT + lane]);
            acc += w0 * h0; acc += w1 * h1; acc += w2 * h2; acc += w3 * h3;
        }
        for (; j < deg; ++j) {
            int   sj = __shfl(s, j, 64);
            float wj = __shfl(w, j, 64);
            acc += wj * b2f(hb[(long)sj * C_OUT + lane]);
        }
    } else {
        float mx = asi;
        for (int b = 0; b < deg; b += 64) {
            int idx = b + lane;
            if (idx < deg) mx = fmaxf(mx, as[csr[start + idx]]);
        }
        #pragma unroll
        for (int o = 32; o > 0; o >>= 1) mx = fmaxf(mx, __shfl_xor(mx, o, 64));
        const float m = lrelu(adi + mx);
        const float wself = __expf(lrelu(adi + asi) - m);
        acc = wself * b2f(hb[(long)i * C_OUT + lane]);
        den = wself;
        for (int b = 0; b < deg; b += 64) {
            int idx = b + lane;
            int s = 0; float w = 0.f;
            if (idx < deg) {
                s = csr[start + idx];
                w = __expf(lrelu(adi + as[s]) - m);
            }
            const int cnt = min(64, deg - b);
            for (int j = 0; j < cnt; ++j) {
                int   sj = __shfl(s, j, 64);
                float wj = __shfl(w, j, 64);
                acc += wj * b2f(hb[(long)sj * C_OUT + lane]);
            }
            float wsum = w;
            #pragma unroll
            for (int o = 32; o > 0; o >>= 1) wsum += __shfl_xor(wsum, o, 64);
            den += wsum;
        }
    }
    out[(long)i * C_OUT + lane] = acc / (den + 1e-16f);
}

extern "C" void kernel_launch(void* const* d_in, const int* in_sizes, int n_in,
                              void* d_out, int out_size, void* d_ws, size_t ws_size,
                              hipStream_t stream) {
    const float* x   = (const float*)d_in[0];
    const int*   ei  = (const int*)d_in[1];
    const int*   nid = (const int*)d_in[2];
    const float* W   = (const float*)d_in[3];
    const float* Wid = (const float*)d_in[4];
    const float* att = (const float*)d_in[5];
    float* out = (float*)d_out;

    char* ws = (char*)d_ws;
    float* h     = (float*)(ws);                   // 25,600,000 B
    int2*  binned = (int2*)(ws);                   // 12,800,000 B (aliases h; used before h is written)
    float* ad    = (float*)(ws + 25600000);        //    400,000 B
    float* as    = (float*)(ws + 26000000);        //    400,000 B
    int*   cur   = (int*)  (ws + 26400000);        //    400,000 B
    int*   csr   = (int*)  (ws + 26800000);        //  6,400,000 B
    __hip_bfloat16* hb = (__hip_bfloat16*)(ws + 33200000);  // 12,800,000 B
    int*   bkcnt = (int*)  (ws + 46000000);        //      1,568 B
    int*   bkoff = (int*)  (ws + 46002000);        //      1,568 B
    int*   bkcur = (int*)  (ws + 46004000);        //      1,568 B

    // CSR build (uses binned region; h written only afterwards)
    hipMemsetAsync(bkcnt, 0, (NBUCK + 1) * sizeof(int), stream);
    k_bhist<<<NBINBLK, 256, 0, stream>>>(ei, bkcnt);
    k_bscan<<<1, 512, 0, stream>>>(bkcnt, bkoff, bkcur);
    k_bin<<<NBINBLK, 256, 0, stream>>>(ei, bkcur, binned);
    k_place<<<NBUCK, 256, 0, stream>>>(binned, bkoff, csr, cur);
    // feature path
    k_gemm<<<782, 256, 0, stream>>>(x, W, h);
    k_id<<<79, 256, 0, stream>>>(x, Wid, nid, h);
    k_scores<<<25000, 256, 0, stream>>>(h, att, ad, as, hb);
    k_gather<<<25000, 256, 0, stream>>>(cur, csr, hb, ad, as, out);
}

// Round 5
// 167.194 us; speedup vs baseline: 4.8853x; 1.5201x over previous
//
#include <hip/hip_runtime.h>
#include <hip/hip_bf16.h>

#define N_NODES 100000
#define E_EDGES 1600000
#define DIN 256
#define C_OUT 64
#define NID_CNT 10000
#define NEG 0.2f
#define NBUCK 391   // ceil(N_NODES/256) coarse buckets (dst >> 8)
#define NBINBLK 391 // ceil(E_EDGES/4096)
#define GEMM_BLOCKS 782  // ceil(100000/128)

typedef short bf16x8 __attribute__((ext_vector_type(8)));
typedef float f32x4  __attribute__((ext_vector_type(4)));

__device__ __forceinline__ float lrelu(float x) { return x > 0.f ? x : NEG * x; }
__device__ __forceinline__ float b2f(__hip_bfloat16 v) { return __bfloat162float(v); }
__device__ __forceinline__ unsigned short f2bs(float f) {
    __hip_bfloat16 b = __float2bfloat16(f);
    return *reinterpret_cast<unsigned short*>(&b);
}

// ---------------- prep: W/Wid transpose+cvt to bf16, id multiplicity ----------------

__global__ __launch_bounds__(256) void k_cvt(const float* __restrict__ W,
                                             const float* __restrict__ Wid,
                                             unsigned short* __restrict__ WtG,
                                             unsigned short* __restrict__ WidtG) {
    const int t = blockIdx.x * 256 + threadIdx.x;  // 0..32767
    if (t >= 2 * DIN * C_OUT) return;
    const int mat = t >> 14;
    const int r = t & 16383;
    const int k = r >> 6, c = r & 63;
    if (mat == 0) WtG[c * DIN + k] = f2bs(W[(long)k * C_OUT + c]);
    else          WidtG[c * DIN + k] = f2bs(Wid[(long)k * C_OUT + c]);
}

__global__ __launch_bounds__(256) void k_cnt(const int* __restrict__ nid,
                                             float* __restrict__ cnt) {
    const int t = blockIdx.x * 256 + threadIdx.x;
    if (t < NID_CNT) atomicAdd(&cnt[nid[t]], 1.0f);
}

// ---------------- CSR build: two-level counting sort ----------------

__global__ __launch_bounds__(256) void k_bhist(const int* __restrict__ ei,
                                               int* __restrict__ bkcnt) {
    __shared__ int cnt[NBUCK];
    const int tid = threadIdx.x;
    for (int i = tid; i < NBUCK; i += 256) cnt[i] = 0;
    __syncthreads();
    const int e0 = blockIdx.x * 4096;
    #pragma unroll
    for (int j = 0; j < 16; ++j) {
        int e = e0 + j * 256 + tid;
        if (e < E_EDGES) atomicAdd(&cnt[ei[E_EDGES + e] >> 8], 1);
    }
    __syncthreads();
    for (int i = tid; i < NBUCK; i += 256)
        if (cnt[i]) atomicAdd(&bkcnt[i], cnt[i]);
}

__global__ __launch_bounds__(512) void k_bscan(const int* __restrict__ bkcnt,
                                               int* __restrict__ bkoff,
                                               int* __restrict__ bkcur) {
    __shared__ int tmp[512];
    const int tid = threadIdx.x;
    const int v = (tid < NBUCK) ? bkcnt[tid] : 0;
    tmp[tid] = v;
    __syncthreads();
    for (int o = 1; o < 512; o <<= 1) {
        int t = (tid >= o) ? tmp[tid - o] : 0;
        __syncthreads();
        tmp[tid] += t;
        __syncthreads();
    }
    if (tid < NBUCK) {
        int excl = tmp[tid] - v;
        bkoff[tid] = excl;
        bkcur[tid] = excl;
        if (tid == NBUCK - 1) bkoff[NBUCK] = tmp[tid];
    }
}

__global__ __launch_bounds__(256) void k_bin(const int* __restrict__ ei,
                                             int* __restrict__ bkcur,
                                             int2* __restrict__ binned) {
    __shared__ int cnt[NBUCK];
    __shared__ int base[NBUCK];
    __shared__ int lcur[NBUCK];
    const int tid = threadIdx.x;
    for (int i = tid; i < NBUCK; i += 256) cnt[i] = 0;
    __syncthreads();
    const int e0 = blockIdx.x * 4096;
    int s[16], d[16];
    #pragma unroll
    for (int j = 0; j < 16; ++j) {
        int e = e0 + j * 256 + tid;
        if (e < E_EDGES) {
            s[j] = ei[e];
            d[j] = ei[E_EDGES + e];
            atomicAdd(&cnt[d[j] >> 8], 1);
        } else d[j] = -1;
    }
    __syncthreads();
    for (int i = tid; i < NBUCK; i += 256) {
        base[i] = cnt[i] ? atomicAdd(&bkcur[i], cnt[i]) : 0;
        lcur[i] = 0;
    }
    __syncthreads();
    #pragma unroll
    for (int j = 0; j < 16; ++j) {
        if (d[j] >= 0) {
            int b = d[j] >> 8;
            int r = atomicAdd(&lcur[b], 1);
            binned[base[b] + r] = make_int2(s[j], d[j]);
        }
    }
}

__global__ __launch_bounds__(256) void k_place(const int2* __restrict__ binned,
                                               const int* __restrict__ bkoff,
                                               int* __restrict__ csr,
                                               int* __restrict__ cur) {
    __shared__ int ncnt[256];
    __shared__ int tmp[256];
    __shared__ int ncur[256];
    const int tid = threadIdx.x;
    const int b = blockIdx.x;
    const int lo = bkoff[b], hi = bkoff[b + 1];
    const int node0 = b << 8;
    ncnt[tid] = 0;
    __syncthreads();
    for (int e = lo + tid; e < hi; e += 256)
        atomicAdd(&ncnt[binned[e].y - node0], 1);
    __syncthreads();
    const int v = ncnt[tid];
    tmp[tid] = v;
    __syncthreads();
    for (int o = 1; o < 256; o <<= 1) {
        int t = (tid >= o) ? tmp[tid - o] : 0;
        __syncthreads();
        tmp[tid] += t;
        __syncthreads();
    }
    const int incl = tmp[tid];
    if (node0 + tid < N_NODES) cur[node0 + tid] = lo + incl;  // inclusive end
    ncur[tid] = incl - v;
    __syncthreads();
    for (int e = lo + tid; e < hi; e += 256) {
        int2 p = binned[e];
        int r = atomicAdd(&ncur[p.y - node0], 1);
        csr[lo + r] = p.x;
    }
}

// ---------------- fused MFMA GEMM: h = x@W + cnt*(x@Wid); emits hb, ad, as ----------------
// 128 rows x 64 cols per block; 4 waves x 32 rows; mfma_f32_16x16x32_bf16.
// LDS: xs (x chunk, bf16, XOR-swizzled 16B slots), wt/wid (W^T chunks, swizzled).
__global__ __launch_bounds__(256) void k_gemm_fused(const float* __restrict__ x,
                                                    const unsigned short* __restrict__ WtG,
                                                    const unsigned short* __restrict__ WidtG,
                                                    const float* __restrict__ cnt,
                                                    const float* __restrict__ att,
                                                    __hip_bfloat16* __restrict__ hb,
                                                    float* __restrict__ ad,
                                                    float* __restrict__ as) {
    __shared__ __align__(16) char xs[18432];   // x chunk: [128 rows][128B]; epilogue: hb tile [128][144B]
    __shared__ __align__(16) char wt[8192];    // Wt chunk: [64 c][128B]
    __shared__ __align__(16) char wid[8192];
    __shared__ float cnt_lds[128];
    const int tid = threadIdx.x;
    const int w = tid >> 6, l = tid & 63;
    const int g = l >> 4, cl = l & 15;
    const int r0 = blockIdx.x * 128;

    if (tid < 128) cnt_lds[tid] = (r0 + tid < N_NODES) ? cnt[r0 + tid] : 0.f;

    f32x4 acc1[2][4] = {};
    f32x4 acc2[2][4] = {};

    for (int kc = 0; kc < DIN; kc += 64) {
        if (kc) __syncthreads();
        // stage x chunk: 128 rows x 64 k, fp32 -> bf16, swizzled
        #pragma unroll
        for (int i = 0; i < 8; ++i) {
            int f = tid + i * 256;
            int row = f >> 4, q = f & 15;      // q: float4 index (4 k)
            int grow = r0 + row;
            float4 v = make_float4(0.f, 0.f, 0.f, 0.f);
            if (grow < N_NODES) v = *(const float4*)(x + (long)grow * DIN + kc + q * 4);
            uint2 pk;
            pk.x = ((unsigned)f2bs(v.y) << 16) | f2bs(v.x);
            pk.y = ((unsigned)f2bs(v.w) << 16) | f2bs(v.z);
            int byte = row * 128 + ((((q >> 1) ^ (row & 7)) << 4)) + (q & 1) * 8;
            *(uint2*)(xs + byte) = pk;
        }
        // stage W^T / Wid^T chunks: 64 c x 64 k bf16
        #pragma unroll
        for (int i = 0; i < 2; ++i) {
            int f = tid + i * 256;
            int c = f >> 3, s = f & 7;
            int byte = c * 128 + (((s ^ (c & 7)) << 4));
            *(bf16x8*)(wt + byte)  = *(const bf16x8*)(WtG + (long)c * DIN + kc + s * 8);
            *(bf16x8*)(wid + byte) = *(const bf16x8*)(WidtG + (long)c * DIN + kc + s * 8);
        }
        __syncthreads();
        #pragma unroll
        for (int kt = 0; kt < 2; ++kt) {
            const int slot = kt * 4 + g;
            bf16x8 a[2], bw[4], bi[4];
            #pragma unroll
            for (int rt = 0; rt < 2; ++rt) {
                int row = w * 32 + rt * 16 + cl;
                a[rt] = *(const bf16x8*)(xs + row * 128 + ((slot ^ (row & 7)) << 4));
            }
            #pragma unroll
            for (int ct = 0; ct < 4; ++ct) {
                int c = ct * 16 + cl;
                int byte = c * 128 + ((slot ^ (c & 7)) << 4);
                bw[ct] = *(const bf16x8*)(wt + byte);
                bi[ct] = *(const bf16x8*)(wid + byte);
            }
            #pragma unroll
            for (int rt = 0; rt < 2; ++rt)
                #pragma unroll
                for (int ct = 0; ct < 4; ++ct) {
                    acc1[rt][ct] = __builtin_amdgcn_mfma_f32_16x16x32_bf16(a[rt], bw[ct], acc1[rt][ct], 0, 0, 0);
                    acc2[rt][ct] = __builtin_amdgcn_mfma_f32_16x16x32_bf16(a[rt], bi[ct], acc2[rt][ct], 0, 0, 0);
                }
        }
    }
    __syncthreads();  // before reusing xs as hb tile

    // epilogue: h = acc1 + cnt*acc2; ad/as via 16-lane reduce; hb tile -> LDS
    float attv1[4], attv2[4];
    #pragma unroll
    for (int ct = 0; ct < 4; ++ct) {
        attv1[ct] = att[ct * 16 + cl];
        attv2[ct] = att[C_OUT + ct * 16 + cl];
    }
    unsigned short* hbt = (unsigned short*)xs;  // stride 72 elements (144 B)
    #pragma unroll
    for (int rt = 0; rt < 2; ++rt) {
        #pragma unroll
        for (int reg = 0; reg < 4; ++reg) {
            const int rbl = w * 32 + rt * 16 + g * 4 + reg;
            const float cv = cnt_lds[rbl];
            float pd = 0.f, ps = 0.f;
            #pragma unroll
            for (int ct = 0; ct < 4; ++ct) {
                float hv = acc1[rt][ct][reg] + cv * acc2[rt][ct][reg];
                pd += hv * attv1[ct];
                ps += hv * attv2[ct];
                hbt[rbl * 72 + ct * 16 + cl] = f2bs(hv);
            }
            #pragma unroll
            for (int o = 1; o < 16; o <<= 1) {
                pd += __shfl_xor(pd, o, 64);
                ps += __shfl_xor(ps, o, 64);
            }
            if (cl == 0) {
                int grow = r0 + rbl;
                if (grow < N_NODES) { ad[grow] = pd; as[grow] = ps; }
            }
        }
    }
    __syncthreads();
    // coalesced hb copy-out
    #pragma unroll
    for (int i = 0; i < 4; ++i) {
        int f = tid + i * 256;        // 1024 units of 16B
        int row = f >> 3, s = f & 7;
        int grow = r0 + row;
        if (grow < N_NODES) {
            bf16x8 v = *(const bf16x8*)(xs + row * 144 + s * 16);
            *(bf16x8*)((unsigned short*)hb + (long)grow * C_OUT + s * 8) = v;
        }
    }
}

// ---------------- gather ----------------

__global__ __launch_bounds__(256) void k_gather(const int* __restrict__ cur,
                                                const int* __restrict__ csr,
                                                const __hip_bfloat16* __restrict__ hb,
                                                const float* __restrict__ ad,
                                                const float* __restrict__ as,
                                                float* __restrict__ out) {
    const int lane = threadIdx.x & 63;
    const int i = blockIdx.x * 4 + (threadIdx.x >> 6);
    if (i >= N_NODES) return;
    const int end   = cur[i];
    const int start = (i > 0) ? cur[i - 1] : 0;
    const int deg   = end - start;
    const float adi = ad[i];
    const float asi = as[i];
    float acc, den;
    if (deg <= 64) {
        int s = 0; float a = -1e30f;
        if (lane < deg) { s = csr[start + lane]; a = as[s]; }
        float mx = fmaxf(a, asi);
        #pragma unroll
        for (int o = 32; o > 0; o >>= 1) mx = fmaxf(mx, __shfl_xor(mx, o, 64));
        const float m = lrelu(adi + mx);
        float w = (lane < deg) ? __expf(lrelu(adi + a) - m) : 0.f;
        const float wself = __expf(lrelu(adi + asi) - m);
        float wsum = w;
        #pragma unroll
        for (int o = 32; o > 0; o >>= 1) wsum += __shfl_xor(wsum, o, 64);
        den = wself + wsum;
        acc = wself * b2f(hb[(long)i * C_OUT + lane]);
        int j = 0;
        for (; j + 4 <= deg; j += 4) {
            int   s0 = __shfl(s, j, 64),   s1 = __shfl(s, j + 1, 64),
                  s2 = __shfl(s, j + 2, 64), s3 = __shfl(s, j + 3, 64);
            float w0 = __shfl(w, j, 64),   w1 = __shfl(w, j + 1, 64),
                  w2 = __shfl(w, j + 2, 64), w3 = __shfl(w, j + 3, 64);
            float h0 = b2f(hb[(long)s0 * C_OUT + lane]);
            float h1 = b2f(hb[(long)s1 * C_OUT + lane]);
            float h2 = b2f(hb[(long)s2 * C_OUT + lane]);
            float h3 = b2f(hb[(long)s3 * C_OUT + lane]);
            acc += w0 * h0; acc += w1 * h1; acc += w2 * h2; acc += w3 * h3;
        }
        for (; j < deg; ++j) {
            int   sj = __shfl(s, j, 64);
            float wj = __shfl(w, j, 64);
            acc += wj * b2f(hb[(long)sj * C_OUT + lane]);
        }
    } else {
        float mx = asi;
        for (int b = 0; b < deg; b += 64) {
            int idx = b + lane;
            if (idx < deg) mx = fmaxf(mx, as[csr[start + idx]]);
        }
        #pragma unroll
        for (int o = 32; o > 0; o >>= 1) mx = fmaxf(mx, __shfl_xor(mx, o, 64));
        const float m = lrelu(adi + mx);
        const float wself = __expf(lrelu(adi + asi) - m);
        acc = wself * b2f(hb[(long)i * C_OUT + lane]);
        den = wself;
        for (int b = 0; b < deg; b += 64) {
            int idx = b + lane;
            int s = 0; float w = 0.f;
            if (idx < deg) {
                s = csr[start + idx];
                w = __expf(lrelu(adi + as[s]) - m);
            }
            const int cnt2 = min(64, deg - b);
            for (int j = 0; j < cnt2; ++j) {
                int   sj = __shfl(s, j, 64);
                float wj = __shfl(w, j, 64);
                acc += wj * b2f(hb[(long)sj * C_OUT + lane]);
            }
            float wsum = w;
            #pragma unroll
            for (int o = 32; o > 0; o >>= 1) wsum += __shfl_xor(wsum, o, 64);
            den += wsum;
        }
    }
    out[(long)i * C_OUT + lane] = acc / (den + 1e-16f);
}

extern "C" void kernel_launch(void* const* d_in, const int* in_sizes, int n_in,
                              void* d_out, int out_size, void* d_ws, size_t ws_size,
                              hipStream_t stream) {
    const float* x   = (const float*)d_in[0];
    const int*   ei  = (const int*)d_in[1];
    const int*   nid = (const int*)d_in[2];
    const float* W   = (const float*)d_in[3];
    const float* Wid = (const float*)d_in[4];
    const float* att = (const float*)d_in[5];
    float* out = (float*)d_out;

    char* ws = (char*)d_ws;
    __hip_bfloat16* hb = (__hip_bfloat16*)(ws);      // 12,800,000 B
    int2*  binned = (int2*)(ws);                     // aliases hb; used only in CSR phase (before gemm)
    float* ad    = (float*)(ws + 12800000);          //    400,000 B
    float* as    = (float*)(ws + 13200000);          //    400,000 B
    int*   cur   = (int*)  (ws + 13600000);          //    400,000 B
    float* cnt   = (float*)(ws + 14000000);          //    400,000 B
    int*   csr   = (int*)  (ws + 14400000);          //  6,400,000 B
    unsigned short* WtG  = (unsigned short*)(ws + 20800000);  // 32,768 B
    unsigned short* WidG = (unsigned short*)(ws + 20832768);  // 32,768 B
    int*   bkcnt = (int*)  (ws + 20865536);          //  1,568+ B
    int*   bkoff = (int*)  (ws + 20867200);          //  1,568+ B
    int*   bkcur = (int*)  (ws + 20868800);          //  1,568  B

    hipMemsetAsync(bkcnt, 0, (NBUCK + 1) * sizeof(int), stream);
    hipMemsetAsync(cnt, 0, N_NODES * sizeof(float), stream);
    k_cvt<<<128, 256, 0, stream>>>(W, Wid, WtG, WidG);
    k_cnt<<<40, 256, 0, stream>>>(nid, cnt);
    // CSR build (binned aliases hb; strictly before k_gemm_fused)
    k_bhist<<<NBINBLK, 256, 0, stream>>>(ei, bkcnt);
    k_bscan<<<1, 512, 0, stream>>>(bkcnt, bkoff, bkcur);
    k_bin<<<NBINBLK, 256, 0, stream>>>(ei, bkcur, binned);
    k_place<<<NBUCK, 256, 0, stream>>>(binned, bkoff, csr, cur);
    // fused feature path
    k_gemm_fused<<<GEMM_BLOCKS, 256, 0, stream>>>(x, WtG, WidG, cnt, att, hb, ad, as);
    k_gather<<<25000, 256, 0, stream>>>(cur, csr, hb, ad, as, out);
}

// Round 6
// 158.031 us; speedup vs baseline: 5.1685x; 1.0580x over previous
//
#include <hip/hip_runtime.h>
#include <hip/hip_bf16.h>

#define N_NODES 100000
#define E_EDGES 1600000
#define DIN 256
#define C_OUT 64
#define NID_CNT 10000
#define NEG 0.2f
#define NBUCK 391   // ceil(N_NODES/256) coarse buckets (dst >> 8)
#define NBINBLK 391 // ceil(E_EDGES/4096)
#define GEMM_BLOCKS 391  // ceil(100000/256)

typedef short bf16x8 __attribute__((ext_vector_type(8)));
typedef float f32x4  __attribute__((ext_vector_type(4)));

__device__ __forceinline__ float lrelu(float x) { return x > 0.f ? x : NEG * x; }
__device__ __forceinline__ float b2f(__hip_bfloat16 v) { return __bfloat162float(v); }
__device__ __forceinline__ unsigned short f2bs(float f) {
    __hip_bfloat16 b = __float2bfloat16(f);
    return *reinterpret_cast<unsigned short*>(&b);
}
__device__ __forceinline__ bf16x8 pack8(float4 a, float4 b) {
    bf16x8 r;
    r[0] = (short)f2bs(a.x); r[1] = (short)f2bs(a.y);
    r[2] = (short)f2bs(a.z); r[3] = (short)f2bs(a.w);
    r[4] = (short)f2bs(b.x); r[5] = (short)f2bs(b.y);
    r[6] = (short)f2bs(b.z); r[7] = (short)f2bs(b.w);
    return r;
}

// ---------------- prep: W/Wid transpose+cvt to bf16, id multiplicity ----------------

__global__ __launch_bounds__(256) void k_cvt(const float* __restrict__ W,
                                             const float* __restrict__ Wid,
                                             unsigned short* __restrict__ WtG,
                                             unsigned short* __restrict__ WidtG) {
    const int t = blockIdx.x * 256 + threadIdx.x;  // 0..32767
    if (t >= 2 * DIN * C_OUT) return;
    const int mat = t >> 14;
    const int r = t & 16383;
    const int k = r >> 6, c = r & 63;
    if (mat == 0) WtG[c * DIN + k] = f2bs(W[(long)k * C_OUT + c]);
    else          WidtG[c * DIN + k] = f2bs(Wid[(long)k * C_OUT + c]);
}

__global__ __launch_bounds__(256) void k_cnt(const int* __restrict__ nid,
                                             float* __restrict__ cnt) {
    const int t = blockIdx.x * 256 + threadIdx.x;
    if (t < NID_CNT) atomicAdd(&cnt[nid[t]], 1.0f);
}

// ---------------- CSR build: two-level counting sort ----------------

__global__ __launch_bounds__(256) void k_bhist(const int* __restrict__ ei,
                                               int* __restrict__ bkcnt) {
    __shared__ int cnt[NBUCK];
    const int tid = threadIdx.x;
    for (int i = tid; i < NBUCK; i += 256) cnt[i] = 0;
    __syncthreads();
    const int e0 = blockIdx.x * 4096;
    #pragma unroll
    for (int j = 0; j < 16; ++j) {
        int e = e0 + j * 256 + tid;
        if (e < E_EDGES) atomicAdd(&cnt[ei[E_EDGES + e] >> 8], 1);
    }
    __syncthreads();
    for (int i = tid; i < NBUCK; i += 256)
        if (cnt[i]) atomicAdd(&bkcnt[i], cnt[i]);
}

__global__ __launch_bounds__(512) void k_bscan(const int* __restrict__ bkcnt,
                                               int* __restrict__ bkoff,
                                               int* __restrict__ bkcur) {
    __shared__ int tmp[512];
    const int tid = threadIdx.x;
    const int v = (tid < NBUCK) ? bkcnt[tid] : 0;
    tmp[tid] = v;
    __syncthreads();
    for (int o = 1; o < 512; o <<= 1) {
        int t = (tid >= o) ? tmp[tid - o] : 0;
        __syncthreads();
        tmp[tid] += t;
        __syncthreads();
    }
    if (tid < NBUCK) {
        int excl = tmp[tid] - v;
        bkoff[tid] = excl;
        bkcur[tid] = excl;
        if (tid == NBUCK - 1) bkoff[NBUCK] = tmp[tid];
    }
}

__global__ __launch_bounds__(256) void k_bin(const int* __restrict__ ei,
                                             int* __restrict__ bkcur,
                                             int2* __restrict__ binned) {
    __shared__ int cnt[NBUCK];
    __shared__ int base[NBUCK];
    __shared__ int lcur[NBUCK];
    const int tid = threadIdx.x;
    for (int i = tid; i < NBUCK; i += 256) cnt[i] = 0;
    __syncthreads();
    const int e0 = blockIdx.x * 4096;
    int s[16], d[16];
    #pragma unroll
    for (int j = 0; j < 16; ++j) {
        int e = e0 + j * 256 + tid;
        if (e < E_EDGES) {
            s[j] = ei[e];
            d[j] = ei[E_EDGES + e];
            atomicAdd(&cnt[d[j] >> 8], 1);
        } else d[j] = -1;
    }
    __syncthreads();
    for (int i = tid; i < NBUCK; i += 256) {
        base[i] = cnt[i] ? atomicAdd(&bkcur[i], cnt[i]) : 0;
        lcur[i] = 0;
    }
    __syncthreads();
    #pragma unroll
    for (int j = 0; j < 16; ++j) {
        if (d[j] >= 0) {
            int b = d[j] >> 8;
            int r = atomicAdd(&lcur[b], 1);
            binned[base[b] + r] = make_int2(s[j], d[j]);
        }
    }
}

__global__ __launch_bounds__(256) void k_place(const int2* __restrict__ binned,
                                               const int* __restrict__ bkoff,
                                               int* __restrict__ csr,
                                               int* __restrict__ cur) {
    __shared__ int ncnt[256];
    __shared__ int tmp[256];
    __shared__ int ncur[256];
    const int tid = threadIdx.x;
    const int b = blockIdx.x;
    const int lo = bkoff[b], hi = bkoff[b + 1];
    const int node0 = b << 8;
    ncnt[tid] = 0;
    __syncthreads();
    for (int e = lo + tid; e < hi; e += 256)
        atomicAdd(&ncnt[binned[e].y - node0], 1);
    __syncthreads();
    const int v = ncnt[tid];
    tmp[tid] = v;
    __syncthreads();
    for (int o = 1; o < 256; o <<= 1) {
        int t = (tid >= o) ? tmp[tid - o] : 0;
        __syncthreads();
        tmp[tid] += t;
        __syncthreads();
    }
    const int incl = tmp[tid];
    if (node0 + tid < N_NODES) cur[node0 + tid] = lo + incl;  // inclusive end
    ncur[tid] = incl - v;
    __syncthreads();
    for (int e = lo + tid; e < hi; e += 256) {
        int2 p = binned[e];
        int r = atomicAdd(&ncur[p.y - node0], 1);
        csr[lo + r] = p.x;
    }
}

// ---------------- fused MFMA GEMM: h = x@W + cnt*(x@Wid); emits hb, ad, as ----------------
// 512 thr = 8 waves x 32 rows = 256 rows/block. W^T/Wid^T staged ONCE in LDS
// (swizzled); A-fragments stream global->reg with fp32->bf16 pack; NO per-chunk
// barrier -> latency hidden by ILP (unrolled 8 k-steps) + TLP (2 blocks/CU).
__global__ __launch_bounds__(512, 4) void k_gemm_fused(const float* __restrict__ x,
                                                       const unsigned short* __restrict__ WtG,
                                                       const unsigned short* __restrict__ WidtG,
                                                       const float* __restrict__ cnt,
                                                       const float* __restrict__ att,
                                                       __hip_bfloat16* __restrict__ hb,
                                                       float* __restrict__ ad,
                                                       float* __restrict__ as) {
    __shared__ __align__(16) char wlds[65536];  // wt [64c][512B] swz; wid at +32768; epilogue: hb tile [256][144B]
    __shared__ float cnt_lds[256];
    const int tid = threadIdx.x;
    const int w = tid >> 6, l = tid & 63;
    const int g = l >> 4, cl = l & 15;
    const int r0 = blockIdx.x * 256;

    // stage W^T / Wid^T once (64 KB), swizzled: byte = c*512 + ((s ^ (c&7))<<4)
    #pragma unroll
    for (int i = 0; i < 4; ++i) {
        int f = tid + i * 512;     // 0..2047 chunks of 16B
        int c = f >> 5, s = f & 31;
        int byte = c * 512 + ((s ^ (c & 7)) << 4);
        *(bf16x8*)(wlds + byte)         = *(const bf16x8*)(WtG + (long)c * DIN + s * 8);
        *(bf16x8*)(wlds + 32768 + byte) = *(const bf16x8*)(WidtG + (long)c * DIN + s * 8);
    }
    if (tid < 256) cnt_lds[tid] = (r0 + tid < N_NODES) ? cnt[r0 + tid] : 0.f;
    __syncthreads();

    f32x4 acc1[2][4] = {};
    f32x4 acc2[2][4] = {};

    const int row0 = r0 + w * 32 + cl;   // A rows: rt*16 offset
    const float* xp0 = x + (long)min(row0, N_NODES - 1) * DIN + g * 8;
    const float* xp1 = x + (long)min(row0 + 16, N_NODES - 1) * DIN + g * 8;

    #pragma unroll
    for (int kt = 0; kt < 8; ++kt) {
        float4 u0 = *(const float4*)(xp0 + kt * 32);
        float4 u1 = *(const float4*)(xp0 + kt * 32 + 4);
        float4 v0 = *(const float4*)(xp1 + kt * 32);
        float4 v1 = *(const float4*)(xp1 + kt * 32 + 4);
        bf16x8 a0 = pack8(u0, u1);
        bf16x8 a1 = pack8(v0, v1);
        #pragma unroll
        for (int ct = 0; ct < 4; ++ct) {
            int c = ct * 16 + cl;
            int byte = c * 512 + (((kt * 4 + g) ^ (c & 7)) << 4);
            bf16x8 bw = *(const bf16x8*)(wlds + byte);
            bf16x8 bi = *(const bf16x8*)(wlds + 32768 + byte);
            acc1[0][ct] = __builtin_amdgcn_mfma_f32_16x16x32_bf16(a0, bw, acc1[0][ct], 0, 0, 0);
            acc1[1][ct] = __builtin_amdgcn_mfma_f32_16x16x32_bf16(a1, bw, acc1[1][ct], 0, 0, 0);
            acc2[0][ct] = __builtin_amdgcn_mfma_f32_16x16x32_bf16(a0, bi, acc2[0][ct], 0, 0, 0);
            acc2[1][ct] = __builtin_amdgcn_mfma_f32_16x16x32_bf16(a1, bi, acc2[1][ct], 0, 0, 0);
        }
    }
    __syncthreads();  // all ds_reads done; wlds reusable as hb tile

    // epilogue: h = acc1 + cnt*acc2; ad/as via 16-lane reduce; hb tile -> LDS
    float attv1[4], attv2[4];
    #pragma unroll
    for (int ct = 0; ct < 4; ++ct) {
        attv1[ct] = att[ct * 16 + cl];
        attv2[ct] = att[C_OUT + ct * 16 + cl];
    }
    unsigned short* hbt = (unsigned short*)wlds;  // stride 72 elements (144 B)
    #pragma unroll
    for (int rt = 0; rt < 2; ++rt) {
        #pragma unroll
        for (int reg = 0; reg < 4; ++reg) {
            const int rbl = w * 32 + rt * 16 + g * 4 + reg;  // 0..255
            const float cv = cnt_lds[rbl];
            float pd = 0.f, ps = 0.f;
            #pragma unroll
            for (int ct = 0; ct < 4; ++ct) {
                float hv = acc1[rt][ct][reg] + cv * acc2[rt][ct][reg];
                pd += hv * attv1[ct];
                ps += hv * attv2[ct];
                hbt[rbl * 72 + ct * 16 + cl] = f2bs(hv);
            }
            #pragma unroll
            for (int o = 1; o < 16; o <<= 1) {
                pd += __shfl_xor(pd, o, 64);
                ps += __shfl_xor(ps, o, 64);
            }
            if (cl == 0) {
                int grow = r0 + rbl;
                if (grow < N_NODES) { ad[grow] = pd; as[grow] = ps; }
            }
        }
    }
    __syncthreads();
    // coalesced hb copy-out: 256 rows x 64 cols bf16 = 2048 x 16B
    #pragma unroll
    for (int i = 0; i < 4; ++i) {
        int f = tid + i * 512;
        int row = f >> 3, s = f & 7;
        int grow = r0 + row;
        if (grow < N_NODES) {
            bf16x8 v = *(const bf16x8*)(wlds + row * 144 + s * 16);
            *(bf16x8*)((unsigned short*)hb + (long)grow * C_OUT + s * 8) = v;
        }
    }
}

// ---------------- gather ----------------

__global__ __launch_bounds__(256) void k_gather(const int* __restrict__ cur,
                                                const int* __restrict__ csr,
                                                const __hip_bfloat16* __restrict__ hb,
                                                const float* __restrict__ ad,
                                                const float* __restrict__ as,
                                                float* __restrict__ out) {
    const int lane = threadIdx.x & 63;
    const int i = blockIdx.x * 4 + (threadIdx.x >> 6);
    if (i >= N_NODES) return;
    const int end   = cur[i];
    const int start = (i > 0) ? cur[i - 1] : 0;
    const int deg   = end - start;
    const float adi = ad[i];
    const float asi = as[i];
    float acc, den;
    if (deg <= 64) {
        int s = 0; float a = -1e30f;
        if (lane < deg) { s = csr[start + lane]; a = as[s]; }
        float mx = fmaxf(a, asi);
        #pragma unroll
        for (int o = 32; o > 0; o >>= 1) mx = fmaxf(mx, __shfl_xor(mx, o, 64));
        const float m = lrelu(adi + mx);
        float w = (lane < deg) ? __expf(lrelu(adi + a) - m) : 0.f;
        const float wself = __expf(lrelu(adi + asi) - m);
        float wsum = w;
        #pragma unroll
        for (int o = 32; o > 0; o >>= 1) wsum += __shfl_xor(wsum, o, 64);
        den = wself + wsum;
        acc = wself * b2f(hb[(long)i * C_OUT + lane]);
        int j = 0;
        for (; j + 4 <= deg; j += 4) {
            int   s0 = __shfl(s, j, 64),   s1 = __shfl(s, j + 1, 64),
                  s2 = __shfl(s, j + 2, 64), s3 = __shfl(s, j + 3, 64);
            float w0 = __shfl(w, j, 64),   w1 = __shfl(w, j + 1, 64),
                  w2 = __shfl(w, j + 2, 64), w3 = __shfl(w, j + 3, 64);
            float h0 = b2f(hb[(long)s0 * C_OUT + lane]);
            float h1 = b2f(hb[(long)s1 * C_OUT + lane]);
            float h2 = b2f(hb[(long)s2 * C_OUT + lane]);
            float h3 = b2f(hb[(long)s3 * C_OUT + lane]);
            acc += w0 * h0; acc += w1 * h1; acc += w2 * h2; acc += w3 * h3;
        }
        for (; j < deg; ++j) {
            int   sj = __shfl(s, j, 64);
            float wj = __shfl(w, j, 64);
            acc += wj * b2f(hb[(long)sj * C_OUT + lane]);
        }
    } else {
        float mx = asi;
        for (int b = 0; b < deg; b += 64) {
            int idx = b + lane;
            if (idx < deg) mx = fmaxf(mx, as[csr[start + idx]]);
        }
        #pragma unroll
        for (int o = 32; o > 0; o >>= 1) mx = fmaxf(mx, __shfl_xor(mx, o, 64));
        const float m = lrelu(adi + mx);
        const float wself = __expf(lrelu(adi + asi) - m);
        acc = wself * b2f(hb[(long)i * C_OUT + lane]);
        den = wself;
        for (int b = 0; b < deg; b += 64) {
            int idx = b + lane;
            int s = 0; float w = 0.f;
            if (idx < deg) {
                s = csr[start + idx];
                w = __expf(lrelu(adi + as[s]) - m);
            }
            const int cnt2 = min(64, deg - b);
            for (int j = 0; j < cnt2; ++j) {
                int   sj = __shfl(s, j, 64);
                float wj = __shfl(w, j, 64);
                acc += wj * b2f(hb[(long)sj * C_OUT + lane]);
            }
            float wsum = w;
            #pragma unroll
            for (int o = 32; o > 0; o >>= 1) wsum += __shfl_xor(wsum, o, 64);
            den += wsum;
        }
    }
    out[(long)i * C_OUT + lane] = acc / (den + 1e-16f);
}

extern "C" void kernel_launch(void* const* d_in, const int* in_sizes, int n_in,
                              void* d_out, int out_size, void* d_ws, size_t ws_size,
                              hipStream_t stream) {
    const float* x   = (const float*)d_in[0];
    const int*   ei  = (const int*)d_in[1];
    const int*   nid = (const int*)d_in[2];
    const float* W   = (const float*)d_in[3];
    const float* Wid = (const float*)d_in[4];
    const float* att = (const float*)d_in[5];
    float* out = (float*)d_out;

    char* ws = (char*)d_ws;
    __hip_bfloat16* hb = (__hip_bfloat16*)(ws);      // 12,800,000 B
    int2*  binned = (int2*)(ws);                     // aliases hb; used only in CSR phase (before gemm)
    float* ad    = (float*)(ws + 12800000);          //    400,000 B
    float* as    = (float*)(ws + 13200000);          //    400,000 B
    int*   cur   = (int*)  (ws + 13600000);          //    400,000 B
    float* cnt   = (float*)(ws + 14000000);          //    400,000 B
    int*   csr   = (int*)  (ws + 14400000);          //  6,400,000 B
    unsigned short* WtG  = (unsigned short*)(ws + 20800000);  // 32,768 B
    unsigned short* WidG = (unsigned short*)(ws + 20832768);  // 32,768 B
    int*   bkcnt = (int*)  (ws + 20865536);          //  1,568+ B
    int*   bkoff = (int*)  (ws + 20867200);          //  1,568+ B
    int*   bkcur = (int*)  (ws + 20868800);          //  1,568  B

    hipMemsetAsync(bkcnt, 0, (NBUCK + 1) * sizeof(int), stream);
    hipMemsetAsync(cnt, 0, N_NODES * sizeof(float), stream);
    k_cvt<<<128, 256, 0, stream>>>(W, Wid, WtG, WidG);
    k_cnt<<<40, 256, 0, stream>>>(nid, cnt);
    // CSR build (binned aliases hb; strictly before k_gemm_fused)
    k_bhist<<<NBINBLK, 256, 0, stream>>>(ei, bkcnt);
    k_bscan<<<1, 512, 0, stream>>>(bkcnt, bkoff, bkcur);
    k_bin<<<NBINBLK, 256, 0, stream>>>(ei, bkcur, binned);
    k_place<<<NBUCK, 256, 0, stream>>>(binned, bkoff, csr, cur);
    // fused feature path
    k_gemm_fused<<<GEMM_BLOCKS, 512, 0, stream>>>(x, WtG, WidG, cnt, att, hb, ad, as);
    k_gather<<<25000, 256, 0, stream>>>(cur, csr, hb, ad, as, out);
}

// Round 7
// 140.178 us; speedup vs baseline: 5.8268x; 1.1274x over previous
//
#include <hip/hip_runtime.h>
#include <hip/hip_bf16.h>

#define N_NODES 100000
#define E_EDGES 1600000
#define DIN 256
#define C_OUT 64
#define NID_CNT 10000
#define NEG 0.2f
#define NBUCK 391   // ceil(N_NODES/256) coarse buckets (dst >> 8)
#define NBINBLK 391 // ceil(E_EDGES/4096)
#define GEMM_BLOCKS 391  // ceil(100000/256)

typedef short bf16x8 __attribute__((ext_vector_type(8)));
typedef float f32x4  __attribute__((ext_vector_type(4)));

__device__ __forceinline__ float lrelu(float x) { return x > 0.f ? x : NEG * x; }
__device__ __forceinline__ float b2f(__hip_bfloat16 v) { return __bfloat162float(v); }
__device__ __forceinline__ unsigned short f2bs(float f) {
    __hip_bfloat16 b = __float2bfloat16(f);
    return *reinterpret_cast<unsigned short*>(&b);
}
__device__ __forceinline__ bf16x8 pack8(float4 a, float4 b) {
    bf16x8 r;
    r[0] = (short)f2bs(a.x); r[1] = (short)f2bs(a.y);
    r[2] = (short)f2bs(a.z); r[3] = (short)f2bs(a.w);
    r[4] = (short)f2bs(b.x); r[5] = (short)f2bs(b.y);
    r[6] = (short)f2bs(b.z); r[7] = (short)f2bs(b.w);
    return r;
}
// bf16x2 (packed in u32) -> two floats
__device__ __forceinline__ float2 unpk2(unsigned u) {
    return make_float2(__uint_as_float(u << 16), __uint_as_float(u & 0xffff0000u));
}

// ---------------- merged prep: W/Wid cvt+transpose | id multiplicity | bucket hist ----------------
__global__ __launch_bounds__(256) void k_prep(const float* __restrict__ W,
                                              const float* __restrict__ Wid,
                                              unsigned short* __restrict__ WtG,
                                              unsigned short* __restrict__ WidtG,
                                              const int* __restrict__ nid,
                                              float* __restrict__ cnt,
                                              const int* __restrict__ ei,
                                              int* __restrict__ bkcnt) {
    __shared__ int lcnt[NBUCK];
    const int b = blockIdx.x;
    const int tid = threadIdx.x;
    if (b < 128) {                       // cvt: 32768 elements
        const int t = b * 256 + tid;
        const int mat = t >> 14;
        const int r = t & 16383;
        const int k = r >> 6, c = r & 63;
        if (mat == 0) WtG[c * DIN + k] = f2bs(W[(long)k * C_OUT + c]);
        else          WidtG[c * DIN + k] = f2bs(Wid[(long)k * C_OUT + c]);
    } else if (b < 168) {                // cnt: 10000 ids
        const int t = (b - 128) * 256 + tid;
        if (t < NID_CNT) atomicAdd(&cnt[nid[t]], 1.0f);
    } else {                             // bhist: 391 blocks x 4096 edges
        for (int i = tid; i < NBUCK; i += 256) lcnt[i] = 0;
        __syncthreads();
        const int e0 = (b - 168) * 4096;
        #pragma unroll
        for (int j = 0; j < 16; ++j) {
            int e = e0 + j * 256 + tid;
            if (e < E_EDGES) atomicAdd(&lcnt[ei[E_EDGES + e] >> 8], 1);
        }
        __syncthreads();
        for (int i = tid; i < NBUCK; i += 256)
            if (lcnt[i]) atomicAdd(&bkcnt[i], lcnt[i]);
    }
}

// ---------------- CSR build: two-level counting sort ----------------

__global__ __launch_bounds__(512) void k_bscan(const int* __restrict__ bkcnt,
                                               int* __restrict__ bkoff,
                                               int* __restrict__ bkcur) {
    __shared__ int tmp[512];
    const int tid = threadIdx.x;
    const int v = (tid < NBUCK) ? bkcnt[tid] : 0;
    tmp[tid] = v;
    __syncthreads();
    for (int o = 1; o < 512; o <<= 1) {
        int t = (tid >= o) ? tmp[tid - o] : 0;
        __syncthreads();
        tmp[tid] += t;
        __syncthreads();
    }
    if (tid < NBUCK) {
        int excl = tmp[tid] - v;
        bkoff[tid] = excl;
        bkcur[tid] = excl;
        if (tid == NBUCK - 1) bkoff[NBUCK] = tmp[tid];
    }
}

__global__ __launch_bounds__(256) void k_bin(const int* __restrict__ ei,
                                             int* __restrict__ bkcur,
                                             int2* __restrict__ binned) {
    __shared__ int cnt[NBUCK];
    __shared__ int base[NBUCK];
    __shared__ int lcur[NBUCK];
    const int tid = threadIdx.x;
    for (int i = tid; i < NBUCK; i += 256) cnt[i] = 0;
    __syncthreads();
    const int e0 = blockIdx.x * 4096;
    int s[16], d[16];
    #pragma unroll
    for (int j = 0; j < 16; ++j) {
        int e = e0 + j * 256 + tid;
        if (e < E_EDGES) {
            s[j] = ei[e];
            d[j] = ei[E_EDGES + e];
            atomicAdd(&cnt[d[j] >> 8], 1);
        } else d[j] = -1;
    }
    __syncthreads();
    for (int i = tid; i < NBUCK; i += 256) {
        base[i] = cnt[i] ? atomicAdd(&bkcur[i], cnt[i]) : 0;
        lcur[i] = 0;
    }
    __syncthreads();
    #pragma unroll
    for (int j = 0; j < 16; ++j) {
        if (d[j] >= 0) {
            int b = d[j] >> 8;
            int r = atomicAdd(&lcur[b], 1);
            binned[base[b] + r] = make_int2(s[j], d[j]);
        }
    }
}

__global__ __launch_bounds__(256) void k_place(const int2* __restrict__ binned,
                                               const int* __restrict__ bkoff,
                                               int* __restrict__ csr,
                                               int* __restrict__ cur) {
    __shared__ int ncnt[256];
    __shared__ int tmp[256];
    __shared__ int ncur[256];
    const int tid = threadIdx.x;
    const int b = blockIdx.x;
    const int lo = bkoff[b], hi = bkoff[b + 1];
    const int node0 = b << 8;
    ncnt[tid] = 0;
    __syncthreads();
    for (int e = lo + tid; e < hi; e += 256)
        atomicAdd(&ncnt[binned[e].y - node0], 1);
    __syncthreads();
    const int v = ncnt[tid];
    tmp[tid] = v;
    __syncthreads();
    for (int o = 1; o < 256; o <<= 1) {
        int t = (tid >= o) ? tmp[tid - o] : 0;
        __syncthreads();
        tmp[tid] += t;
        __syncthreads();
    }
    const int incl = tmp[tid];
    if (node0 + tid < N_NODES) cur[node0 + tid] = lo + incl;  // inclusive end
    ncur[tid] = incl - v;
    __syncthreads();
    for (int e = lo + tid; e < hi; e += 256) {
        int2 p = binned[e];
        int r = atomicAdd(&ncur[p.y - node0], 1);
        csr[lo + r] = p.x;
    }
}

// ---------------- fused MFMA GEMM: h = x@W + cnt*(x@Wid); emits hb, ad, as ----------------
__global__ __launch_bounds__(512, 4) void k_gemm_fused(const float* __restrict__ x,
                                                       const unsigned short* __restrict__ WtG,
                                                       const unsigned short* __restrict__ WidtG,
                                                       const float* __restrict__ cnt,
                                                       const float* __restrict__ att,
                                                       __hip_bfloat16* __restrict__ hb,
                                                       float* __restrict__ ad,
                                                       float* __restrict__ as) {
    __shared__ __align__(16) char wlds[65536];  // wt [64c][512B] swz; wid at +32768; epilogue: hb tile [256][144B]
    __shared__ float cnt_lds[256];
    const int tid = threadIdx.x;
    const int w = tid >> 6, l = tid & 63;
    const int g = l >> 4, cl = l & 15;
    const int r0 = blockIdx.x * 256;

    #pragma unroll
    for (int i = 0; i < 4; ++i) {
        int f = tid + i * 512;     // 0..2047 chunks of 16B
        int c = f >> 5, s = f & 31;
        int byte = c * 512 + ((s ^ (c & 7)) << 4);
        *(bf16x8*)(wlds + byte)         = *(const bf16x8*)(WtG + (long)c * DIN + s * 8);
        *(bf16x8*)(wlds + 32768 + byte) = *(const bf16x8*)(WidtG + (long)c * DIN + s * 8);
    }
    if (tid < 256) cnt_lds[tid] = (r0 + tid < N_NODES) ? cnt[r0 + tid] : 0.f;
    __syncthreads();

    f32x4 acc1[2][4] = {};
    f32x4 acc2[2][4] = {};

    const int row0 = r0 + w * 32 + cl;
    const float* xp0 = x + (long)min(row0, N_NODES - 1) * DIN + g * 8;
    const float* xp1 = x + (long)min(row0 + 16, N_NODES - 1) * DIN + g * 8;

    #pragma unroll
    for (int kt = 0; kt < 8; ++kt) {
        float4 u0 = *(const float4*)(xp0 + kt * 32);
        float4 u1 = *(const float4*)(xp0 + kt * 32 + 4);
        float4 v0 = *(const float4*)(xp1 + kt * 32);
        float4 v1 = *(const float4*)(xp1 + kt * 32 + 4);
        bf16x8 a0 = pack8(u0, u1);
        bf16x8 a1 = pack8(v0, v1);
        #pragma unroll
        for (int ct = 0; ct < 4; ++ct) {
            int c = ct * 16 + cl;
            int byte = c * 512 + (((kt * 4 + g) ^ (c & 7)) << 4);
            bf16x8 bw = *(const bf16x8*)(wlds + byte);
            bf16x8 bi = *(const bf16x8*)(wlds + 32768 + byte);
            acc1[0][ct] = __builtin_amdgcn_mfma_f32_16x16x32_bf16(a0, bw, acc1[0][ct], 0, 0, 0);
            acc1[1][ct] = __builtin_amdgcn_mfma_f32_16x16x32_bf16(a1, bw, acc1[1][ct], 0, 0, 0);
            acc2[0][ct] = __builtin_amdgcn_mfma_f32_16x16x32_bf16(a0, bi, acc2[0][ct], 0, 0, 0);
            acc2[1][ct] = __builtin_amdgcn_mfma_f32_16x16x32_bf16(a1, bi, acc2[1][ct], 0, 0, 0);
        }
    }
    __syncthreads();

    float attv1[4], attv2[4];
    #pragma unroll
    for (int ct = 0; ct < 4; ++ct) {
        attv1[ct] = att[ct * 16 + cl];
        attv2[ct] = att[C_OUT + ct * 16 + cl];
    }
    unsigned short* hbt = (unsigned short*)wlds;  // stride 72 elements (144 B)
    #pragma unroll
    for (int rt = 0; rt < 2; ++rt) {
        #pragma unroll
        for (int reg = 0; reg < 4; ++reg) {
            const int rbl = w * 32 + rt * 16 + g * 4 + reg;
            const float cv = cnt_lds[rbl];
            float pd = 0.f, ps = 0.f;
            #pragma unroll
            for (int ct = 0; ct < 4; ++ct) {
                float hv = acc1[rt][ct][reg] + cv * acc2[rt][ct][reg];
                pd += hv * attv1[ct];
                ps += hv * attv2[ct];
                hbt[rbl * 72 + ct * 16 + cl] = f2bs(hv);
            }
            #pragma unroll
            for (int o = 1; o < 16; o <<= 1) {
                pd += __shfl_xor(pd, o, 64);
                ps += __shfl_xor(ps, o, 64);
            }
            if (cl == 0) {
                int grow = r0 + rbl;
                if (grow < N_NODES) { ad[grow] = pd; as[grow] = ps; }
            }
        }
    }
    __syncthreads();
    #pragma unroll
    for (int i = 0; i < 4; ++i) {
        int f = tid + i * 512;
        int row = f >> 3, s = f & 7;
        int grow = r0 + row;
        if (grow < N_NODES) {
            bf16x8 v = *(const bf16x8*)(wlds + row * 144 + s * 16);
            *(bf16x8*)((unsigned short*)hb + (long)grow * C_OUT + s * 8) = v;
        }
    }
}

// ---------------- gather: 2 nodes/wave (32-lane groups), 2 channels/lane (bf16x2) ----------------
__global__ __launch_bounds__(256) void k_gather(const int* __restrict__ cur,
                                                const int* __restrict__ csr,
                                                const unsigned* __restrict__ hb2,
                                                const float* __restrict__ ad,
                                                const float* __restrict__ as,
                                                float* __restrict__ out) {
    const int lane = threadIdx.x & 63;
    const int lg = lane & 31;                  // lane in group
    const int gb = lane & 32;                  // group broadcast base
    const int i = blockIdx.x * 8 + ((threadIdx.x >> 6) << 1) + (lane >> 5);
    if (i >= N_NODES) return;
    const int end   = cur[i];
    const int start = (i > 0) ? cur[i - 1] : 0;
    const int deg   = end - start;
    const float adi = ad[i];
    const float asi = as[i];
    float2 acc;
    float den;
    if (deg <= 32) {
        int s = 0; float a = -1e30f;
        if (lg < deg) { s = csr[start + lg]; a = as[s]; }
        float mx = fmaxf(a, asi);
        #pragma unroll
        for (int o = 16; o > 0; o >>= 1) mx = fmaxf(mx, __shfl_xor(mx, o, 64));
        const float m = lrelu(adi + mx);
        float w = (lg < deg) ? __expf(lrelu(adi + a) - m) : 0.f;
        const float wself = __expf(lrelu(adi + asi) - m);
        float wsum = w;
        #pragma unroll
        for (int o = 16; o > 0; o >>= 1) wsum += __shfl_xor(wsum, o, 64);
        den = wself + wsum;
        float2 hv = unpk2(hb2[(long)i * 32 + lg]);
        acc = make_float2(wself * hv.x, wself * hv.y);
        int j = 0;
        for (; j + 4 <= deg; j += 4) {
            int   s0 = __shfl(s, gb + j, 64),     s1 = __shfl(s, gb + j + 1, 64),
                  s2 = __shfl(s, gb + j + 2, 64), s3 = __shfl(s, gb + j + 3, 64);
            float w0 = __shfl(w, gb + j, 64),     w1 = __shfl(w, gb + j + 1, 64),
                  w2 = __shfl(w, gb + j + 2, 64), w3 = __shfl(w, gb + j + 3, 64);
            float2 h0 = unpk2(hb2[(long)s0 * 32 + lg]);
            float2 h1 = unpk2(hb2[(long)s1 * 32 + lg]);
            float2 h2 = unpk2(hb2[(long)s2 * 32 + lg]);
            float2 h3 = unpk2(hb2[(long)s3 * 32 + lg]);
            acc.x += w0 * h0.x; acc.y += w0 * h0.y;
            acc.x += w1 * h1.x; acc.y += w1 * h1.y;
            acc.x += w2 * h2.x; acc.y += w2 * h2.y;
            acc.x += w3 * h3.x; acc.y += w3 * h3.y;
        }
        for (; j < deg; ++j) {
            int   sj = __shfl(s, gb + j, 64);
            float wj = __shfl(w, gb + j, 64);
            float2 hj = unpk2(hb2[(long)sj * 32 + lg]);
            acc.x += wj * hj.x; acc.y += wj * hj.y;
        }
    } else {  // rare: deg > 32
        float mx = asi;
        for (int b = 0; b < deg; b += 32) {
            int idx = b + lg;
            if (idx < deg) mx = fmaxf(mx, as[csr[start + idx]]);
        }
        #pragma unroll
        for (int o = 16; o > 0; o >>= 1) mx = fmaxf(mx, __shfl_xor(mx, o, 64));
        const float m = lrelu(adi + mx);
        const float wself = __expf(lrelu(adi + asi) - m);
        float2 hv = unpk2(hb2[(long)i * 32 + lg]);
        acc = make_float2(wself * hv.x, wself * hv.y);
        den = wself;
        for (int b = 0; b < deg; b += 32) {
            int idx = b + lg;
            int s = 0; float w = 0.f;
            if (idx < deg) {
                s = csr[start + idx];
                w = __expf(lrelu(adi + as[s]) - m);
            }
            const int cnt2 = min(32, deg - b);
            for (int j = 0; j < cnt2; ++j) {
                int   sj = __shfl(s, gb + j, 64);
                float wj = __shfl(w, gb + j, 64);
                float2 hj = unpk2(hb2[(long)sj * 32 + lg]);
                acc.x += wj * hj.x; acc.y += wj * hj.y;
            }
            float wsum = w;
            #pragma unroll
            for (int o = 16; o > 0; o >>= 1) wsum += __shfl_xor(wsum, o, 64);
            den += wsum;
        }
    }
    const float r = 1.f / (den + 1e-16f);
    *(float2*)(out + (long)i * C_OUT + lg * 2) = make_float2(acc.x * r, acc.y * r);
}

extern "C" void kernel_launch(void* const* d_in, const int* in_sizes, int n_in,
                              void* d_out, int out_size, void* d_ws, size_t ws_size,
                              hipStream_t stream) {
    const float* x   = (const float*)d_in[0];
    const int*   ei  = (const int*)d_in[1];
    const int*   nid = (const int*)d_in[2];
    const float* W   = (const float*)d_in[3];
    const float* Wid = (const float*)d_in[4];
    const float* att = (const float*)d_in[5];
    float* out = (float*)d_out;

    char* ws = (char*)d_ws;
    __hip_bfloat16* hb = (__hip_bfloat16*)(ws);      // 12,800,000 B
    int2*  binned = (int2*)(ws);                     // aliases hb; used only in CSR phase (before gemm)
    float* ad    = (float*)(ws + 12800000);          //    400,000 B
    float* as    = (float*)(ws + 13200000);          //    400,000 B
    int*   cur   = (int*)  (ws + 13600000);          //    400,000 B
    float* cnt   = (float*)(ws + 14000000);          //    400,000 B
    int*   csr   = (int*)  (ws + 14400000);          //  6,400,000 B
    unsigned short* WtG  = (unsigned short*)(ws + 20800000);  // 32,768 B
    unsigned short* WidG = (unsigned short*)(ws + 20832768);  // 32,768 B
    int*   bkcnt = (int*)  (ws + 20865536);          //  1,568+ B
    int*   bkoff = (int*)  (ws + 20867200);          //  1,568+ B
    int*   bkcur = (int*)  (ws + 20868800);          //  1,568  B

    hipMemsetAsync(bkcnt, 0, (NBUCK + 1) * sizeof(int), stream);
    hipMemsetAsync(cnt, 0, N_NODES * sizeof(float), stream);
    // merged prep: cvt (128 blocks) | id-count (40) | bucket hist (391)
    k_prep<<<559, 256, 0, stream>>>(W, Wid, WtG, WidG, nid, cnt, ei, bkcnt);
    k_bscan<<<1, 512, 0, stream>>>(bkcnt, bkoff, bkcur);
    k_bin<<<NBINBLK, 256, 0, stream>>>(ei, bkcur, binned);
    k_place<<<NBUCK, 256, 0, stream>>>(binned, bkoff, csr, cur);
    // fused feature path
    k_gemm_fused<<<GEMM_BLOCKS, 512, 0, stream>>>(x, WtG, WidG, cnt, att, hb, ad, as);
    k_gather<<<12500, 256, 0, stream>>>(cur, csr, (const unsigned*)hb, ad, as, out);
}